// Round 1
// baseline (3463.845 us; speedup 1.0000x reference)
//
#include <hip/hip_runtime.h>

#define NN 100000
#define NE 1600000
#define HH 32
#define CC 10
#define GG 64

// ---------------- workspace layout (floats) ----------------
// deg   : [NN]            at 0
// dinv  : [NN]            at NN
// tab   : [16384]         at 2*NN
//    A  : tab[0    .. 960)    A[c][p][j]  (c*96 + p*32 + j)
//    B  : tab[960  .. 1920)   B[c][p][j]
//    hb : tab[1920 .. 2240)   hb[c][j]
//    M  : tab[2240 .. 12480)  M[c][k][j]  (c*1024 + k*32 + j)
//    t  : tab[12480.. 12512)  t[j]
// U    : [NN*32]  (reused as h1raw)
// V    : [NN*32]  (reused as xw2)
// aggC : [NN*32]  (reused as h2raw)
// xw1  : [NN*32]
// pooled:[64*32]
// counts:[64]

__global__ void zero_kernel(float* p, int n) {
    int i = blockIdx.x * 256 + threadIdx.x;
    if (i < n) p[i] = 0.0f;
}

// grid 10 blocks (one per class), 1024 threads
__global__ void precompute_small(const float* __restrict__ fW, const float* __restrict__ fb,
                                 const float* __restrict__ W1, const float* __restrict__ b1,
                                 const float* __restrict__ W2, const float* __restrict__ b2,
                                 const float* __restrict__ g1W, float* __restrict__ tab) {
    int c = blockIdx.x;
    int k = threadIdx.x >> 5;
    int j = threadIdx.x & 31;
    // M[c][k][j] = sum_m W2[k][m] * g1W[3 + 32c + m][j]
    float m = 0.f;
    for (int mm = 0; mm < 32; ++mm)
        m += W2[k * 32 + mm] * g1W[(3 + 32 * c + mm) * 32 + j];
    tab[2240 + c * 1024 + k * 32 + j] = m;

    if (k < 3) {
        float a = 0.f, b = 0.f;
        for (int i = 0; i < 32; ++i) {
            float w = fW[c * 96 + k * 32 + i];
            a += w * W1[i * 32 + j];
            b += w * W1[(32 + i) * 32 + j];
        }
        tab[c * 96 + k * 32 + j] = a;
        tab[960 + c * 96 + k * 32 + j] = b;
    } else if (k == 3) {
        float h = b1[j];
        for (int i = 0; i < 32; ++i)
            h += fb[c * 32 + i] * (W1[i * 32 + j] + W1[(32 + i) * 32 + j]);
        tab[1920 + c * 32 + j] = h;
    } else if (k == 4 && c == 0) {
        float t = 0.f;
        for (int cc2 = 0; cc2 < CC; ++cc2)
            for (int mm = 0; mm < 32; ++mm)
                t += b2[mm] * g1W[(3 + 32 * cc2 + mm) * 32 + j];
        tab[12480 + j] = t;
    }
}

__global__ void deg_kernel(const int* __restrict__ ei, float* __restrict__ deg) {
    int e = blockIdx.x * 256 + threadIdx.x;
    if (e < NE) atomicAdd(&deg[ei[NE + e]], 1.0f);
}

__global__ void dinv_kernel(const float* __restrict__ deg, float* __restrict__ dinv) {
    int n = blockIdx.x * 256 + threadIdx.x;
    if (n < NN) dinv[n] = rsqrtf(deg[n] + 1.0f);
}

// xw1[n][j] = sum_p x[n][p]*g1W[p][j] + deg[n]*t[j]
__global__ void xw1_init(const float* __restrict__ x, const float* __restrict__ g1W,
                         const float* __restrict__ deg, const float* __restrict__ tab,
                         float* __restrict__ xw1) {
    int gid = blockIdx.x * 256 + threadIdx.x;
    if (gid >= NN * 32) return;
    int n = gid >> 5, j = gid & 31;
    float v = deg[n] * tab[12480 + j];
    v += x[n * 3 + 0] * g1W[0 * 32 + j];
    v += x[n * 3 + 1] * g1W[1 * 32 + j];
    v += x[n * 3 + 2] * g1W[2 * 32 + j];
    xw1[gid] = v;
}

// per class: u = x@A_c + hb_c, v = x@B_c ; also zero aggC
__global__ void uv_kernel(const float* __restrict__ x, const float* __restrict__ tab, int c,
                          float* __restrict__ U, float* __restrict__ V, float* __restrict__ aggC) {
    int gid = blockIdx.x * 256 + threadIdx.x;
    if (gid >= NN * 32) return;
    int n = gid >> 5, j = gid & 31;
    const float* A = tab + c * 96;
    const float* B = tab + 960 + c * 96;
    float x0 = x[n * 3], x1 = x[n * 3 + 1], x2 = x[n * 3 + 2];
    float u = tab[1920 + c * 32 + j] + x0 * A[j] + x1 * A[32 + j] + x2 * A[64 + j];
    float v = x0 * B[j] + x1 * B[32 + j] + x2 * B[64 + j];
    U[gid] = u;
    V[gid] = v;
    aggC[gid] = 0.0f;
}

// per class: aggC[col] += relu(U[row] + V[col])
__global__ void edge_hidden(const int* __restrict__ ei, const float* __restrict__ U,
                            const float* __restrict__ V, float* __restrict__ aggC) {
    int gid = blockIdx.x * 256 + threadIdx.x;
    int e = gid >> 5;
    if (e >= NE) return;
    int j = gid & 31;
    int r = ei[e], c = ei[NE + e];
    float h = U[r * 32 + j] + V[c * 32 + j];
    h = fmaxf(h, 0.0f);
    atomicAdd(&aggC[c * 32 + j], h);
}

// xw1[n][j] += sum_k aggC[n][k] * M[c][k][j]
__global__ void fold_kernel(const float* __restrict__ aggC, const float* __restrict__ tab, int c,
                            float* __restrict__ xw1) {
    int gid = blockIdx.x * 256 + threadIdx.x;
    if (gid >= NN * 32) return;
    int n = gid >> 5, j = gid & 31;
    const float* M = tab + 2240 + c * 1024;
    float s = 0.f;
    for (int k = 0; k < 32; ++k) s += aggC[n * 32 + k] * M[k * 32 + j];
    xw1[gid] += s;
}

__global__ void prop_init(const float* __restrict__ xw, const float* __restrict__ dinv,
                          float* __restrict__ out) {
    int gid = blockIdx.x * 256 + threadIdx.x;
    if (gid >= NN * 32) return;
    int n = gid >> 5;
    float d = dinv[n];
    out[gid] = xw[gid] * d * d;
}

__global__ void prop_edge(const int* __restrict__ ei, const float* __restrict__ xw,
                          const float* __restrict__ dinv, float* __restrict__ out) {
    int gid = blockIdx.x * 256 + threadIdx.x;
    int e = gid >> 5;
    if (e >= NE) return;
    int j = gid & 31;
    int r = ei[e], c = ei[NE + e];
    float w = dinv[r] * dinv[c];
    atomicAdd(&out[c * 32 + j], xw[r * 32 + j] * w);
}

// xw2[n][j] = sum_k relu(h1raw[n][k] + g1b[k]) * g2W[k][j]
__global__ void xw2_kernel(const float* __restrict__ h1raw, const float* __restrict__ g1b,
                           const float* __restrict__ g2W, float* __restrict__ xw2) {
    int gid = blockIdx.x * 256 + threadIdx.x;
    if (gid >= NN * 32) return;
    int n = gid >> 5, j = gid & 31;
    float s = 0.f;
    for (int k = 0; k < 32; ++k) {
        float h = fmaxf(h1raw[n * 32 + k] + g1b[k], 0.0f);
        s += h * g2W[k * 32 + j];
    }
    xw2[gid] = s;
}

__global__ void pool_kernel(const float* __restrict__ h2raw, const float* __restrict__ g2b,
                            const int* __restrict__ batch, float* __restrict__ pooled,
                            float* __restrict__ counts) {
    int gid = blockIdx.x * 256 + threadIdx.x;
    if (gid >= NN * 32) return;
    int n = gid >> 5, j = gid & 31;
    float h = fmaxf(h2raw[gid] + g2b[j], 0.0f);
    int g = batch[n];
    atomicAdd(&pooled[g * 32 + j], h);
    if (j == 0) atomicAdd(&counts[g], 1.0f);
}

__global__ void final_kernel(const float* __restrict__ pooled, const float* __restrict__ counts,
                             const float* __restrict__ clsW, const float* __restrict__ clsb,
                             float* __restrict__ out) {
    int tid = threadIdx.x;
    if (tid >= GG * CC) return;
    int g = tid / CC, cc = tid % CC;
    float inv = 1.0f / fmaxf(counts[g], 1.0f);
    float s = clsb[cc];
    for (int j = 0; j < 32; ++j) s += (pooled[g * 32 + j] * inv) * clsW[j * CC + cc];
    out[g * CC + cc] = s;
}

extern "C" void kernel_launch(void* const* d_in, const int* in_sizes, int n_in,
                              void* d_out, int out_size, void* d_ws, size_t ws_size,
                              hipStream_t stream) {
    const float* x    = (const float*)d_in[0];
    const int*   ei   = (const int*)d_in[1];
    const int*   batch= (const int*)d_in[2];
    const float* fW   = (const float*)d_in[3];
    const float* fb   = (const float*)d_in[4];
    const float* W1   = (const float*)d_in[5];
    const float* b1   = (const float*)d_in[6];
    const float* W2   = (const float*)d_in[7];
    const float* b2   = (const float*)d_in[8];
    const float* g1W  = (const float*)d_in[9];
    const float* g1b  = (const float*)d_in[10];
    const float* g2W  = (const float*)d_in[11];
    const float* g2b  = (const float*)d_in[12];
    const float* clsW = (const float*)d_in[13];
    const float* clsb = (const float*)d_in[14];
    float* out = (float*)d_out;

    float* ws = (float*)d_ws;
    float* deg    = ws;
    float* dinv   = ws + NN;
    float* tab    = ws + 2 * NN;
    float* U      = tab + 16384;
    float* V      = U + NN * 32;
    float* aggC   = V + NN * 32;
    float* xw1    = aggC + NN * 32;
    float* pooled = xw1 + NN * 32;
    float* counts = pooled + GG * 32;

    const int nodeElems = NN * 32;
    const int nodeBlocks = (nodeElems + 255) / 256;           // 12500
    const int edgeBlocks = (NE * 32 + 255) / 256;             // 200000

    // zero deg + pooled + counts
    zero_kernel<<<(NN + 255) / 256, 256, 0, stream>>>(deg, NN);
    zero_kernel<<<(GG * 33 + 255) / 256, 256, 0, stream>>>(pooled, GG * 33);

    precompute_small<<<10, 1024, 0, stream>>>(fW, fb, W1, b1, W2, b2, g1W, tab);
    deg_kernel<<<(NE + 255) / 256, 256, 0, stream>>>(ei, deg);
    dinv_kernel<<<(NN + 255) / 256, 256, 0, stream>>>(deg, dinv);
    xw1_init<<<nodeBlocks, 256, 0, stream>>>(x, g1W, deg, tab, xw1);

    for (int c = 0; c < CC; ++c) {
        uv_kernel<<<nodeBlocks, 256, 0, stream>>>(x, tab, c, U, V, aggC);
        edge_hidden<<<edgeBlocks, 256, 0, stream>>>(ei, U, V, aggC);
        fold_kernel<<<nodeBlocks, 256, 0, stream>>>(aggC, tab, c, xw1);
    }

    // GCN layer 1: U <- h1raw
    prop_init<<<nodeBlocks, 256, 0, stream>>>(xw1, dinv, U);
    prop_edge<<<edgeBlocks, 256, 0, stream>>>(ei, xw1, dinv, U);
    // xw2 = relu(h1+b1)@g2W -> V
    xw2_kernel<<<nodeBlocks, 256, 0, stream>>>(U, g1b, g2W, V);
    // GCN layer 2: aggC <- h2raw
    prop_init<<<nodeBlocks, 256, 0, stream>>>(V, dinv, aggC);
    prop_edge<<<edgeBlocks, 256, 0, stream>>>(ei, V, dinv, aggC);
    // pool + classify
    pool_kernel<<<nodeBlocks, 256, 0, stream>>>(aggC, g2b, batch, pooled, counts);
    final_kernel<<<1, 640, 0, stream>>>(pooled, counts, clsW, clsb, out);
}

// Round 2
// 1600.268 us; speedup vs baseline: 2.1645x; 2.1645x over previous
//
#include <hip/hip_runtime.h>

#define NN 100000
#define NE 1600000
#define HH 32
#define CC 10
#define GG 64

// ---------------- workspace layout ----------------
// int   ideg[NN], offs[NN+1], cursor[NN], csr_row[NE]
// float dinv[NN], tab[16384], xw1[NN*32], U[NN*32], V[NN*32], pooled[64*32], counts[64]
// tab:  A[c][p][j] at c*96+p*32+j ; B at +960 ; hb[c][j] at +1920 ; M[c][k][j] at +2240 ; t[j] at +12480

__global__ void zero_int(int* p, int n) {
    int i = blockIdx.x * 256 + threadIdx.x;
    if (i < n) p[i] = 0;
}

__global__ void zero_f(float* p, int n) {
    int i = blockIdx.x * 256 + threadIdx.x;
    if (i < n) p[i] = 0.0f;
}

// grid 10 blocks (one per class), 1024 threads
__global__ void precompute_small(const float* __restrict__ fW, const float* __restrict__ fb,
                                 const float* __restrict__ W1, const float* __restrict__ b1,
                                 const float* __restrict__ W2, const float* __restrict__ b2,
                                 const float* __restrict__ g1W, float* __restrict__ tab) {
    int c = blockIdx.x;
    int k = threadIdx.x >> 5;
    int j = threadIdx.x & 31;
    float m = 0.f;
    for (int mm = 0; mm < 32; ++mm)
        m += W2[k * 32 + mm] * g1W[(3 + 32 * c + mm) * 32 + j];
    tab[2240 + c * 1024 + k * 32 + j] = m;

    if (k < 3) {
        float a = 0.f, b = 0.f;
        for (int i = 0; i < 32; ++i) {
            float w = fW[c * 96 + k * 32 + i];
            a += w * W1[i * 32 + j];
            b += w * W1[(32 + i) * 32 + j];
        }
        tab[c * 96 + k * 32 + j] = a;
        tab[960 + c * 96 + k * 32 + j] = b;
    } else if (k == 3) {
        float h = b1[j];
        for (int i = 0; i < 32; ++i)
            h += fb[c * 32 + i] * (W1[i * 32 + j] + W1[(32 + i) * 32 + j]);
        tab[1920 + c * 32 + j] = h;
    } else if (k == 4 && c == 0) {
        float t = 0.f;
        for (int cc2 = 0; cc2 < CC; ++cc2)
            for (int mm = 0; mm < 32; ++mm)
                t += b2[mm] * g1W[(3 + 32 * cc2 + mm) * 32 + j];
        tab[12480 + j] = t;
    }
}

__global__ void deg_int(const int* __restrict__ ei, int* __restrict__ ideg) {
    int e = blockIdx.x * 256 + threadIdx.x;
    if (e < NE) atomicAdd(&ideg[ei[NE + e]], 1);
}

// single block, 1024 threads: exclusive prefix sum of ideg -> offs, offs[NN] = NE
__global__ void scan_kernel(const int* __restrict__ ideg, int* __restrict__ offs) {
    __shared__ int sums[1024];
    int tid = threadIdx.x;
    const int CH = (NN + 1023) / 1024;  // 98
    int base = tid * CH;
    int s = 0;
    for (int i = 0; i < CH; ++i) {
        int idx = base + i;
        if (idx < NN) s += ideg[idx];
    }
    sums[tid] = s;
    __syncthreads();
    for (int off = 1; off < 1024; off <<= 1) {
        int v = 0;
        if (tid >= off) v = sums[tid - off];
        __syncthreads();
        if (tid >= off) sums[tid] += v;
        __syncthreads();
    }
    int run = (tid == 0) ? 0 : sums[tid - 1];
    for (int i = 0; i < CH; ++i) {
        int idx = base + i;
        if (idx < NN) { offs[idx] = run; run += ideg[idx]; }
    }
    if (tid == 1023) offs[NN] = run;
}

__global__ void prep_nodes(const int* __restrict__ ideg, const int* __restrict__ offs,
                           int* __restrict__ cursor, float* __restrict__ dinv) {
    int n = blockIdx.x * 256 + threadIdx.x;
    if (n < NN) {
        cursor[n] = offs[n];
        dinv[n] = rsqrtf((float)ideg[n] + 1.0f);
    }
}

__global__ void csr_fill(const int* __restrict__ ei, int* __restrict__ cursor,
                         int* __restrict__ csr_row) {
    int e = blockIdx.x * 256 + threadIdx.x;
    if (e < NE) {
        int c = ei[NE + e];
        int pos = atomicAdd(&cursor[c], 1);
        csr_row[pos] = ei[e];
    }
}

// xw1[n][j] = x[n]@g1W[0:3] + ideg[n]*t[j]
__global__ void xw1_init(const float* __restrict__ x, const float* __restrict__ g1W,
                         const int* __restrict__ ideg, const float* __restrict__ tab,
                         float* __restrict__ xw1) {
    int gid = blockIdx.x * 256 + threadIdx.x;
    if (gid >= NN * 32) return;
    int n = gid >> 5, j = gid & 31;
    float v = (float)ideg[n] * tab[12480 + j];
    v += x[n * 3 + 0] * g1W[0 * 32 + j];
    v += x[n * 3 + 1] * g1W[1 * 32 + j];
    v += x[n * 3 + 2] * g1W[2 * 32 + j];
    xw1[gid] = v;
}

// All 10 classes fused: per node n, aggH_c = sum_{r in in(n)} relu(u_c(r)+v_c(n));
// xw1[n][:] += sum_c aggH_c @ M_c.  A/B/hb register-resident per lane, M in LDS.
__global__ __launch_bounds__(256) void edgeconv_fused(
    const float* __restrict__ x, const int* __restrict__ offs,
    const int* __restrict__ csr_row, const float* __restrict__ tab,
    float* __restrict__ xw1) {
    __shared__ float Mlds[10240];
    for (int i = threadIdx.x; i < 10240; i += 256) Mlds[i] = tab[2240 + i];
    int j = threadIdx.x & 31;
    int grp = threadIdx.x >> 5;
    float Areg[CC][3], Breg[CC][3], hbreg[CC];
#pragma unroll
    for (int c = 0; c < CC; ++c) {
#pragma unroll
        for (int p = 0; p < 3; ++p) {
            Areg[c][p] = tab[c * 96 + p * 32 + j];
            Breg[c][p] = tab[960 + c * 96 + p * 32 + j];
        }
        hbreg[c] = tab[1920 + c * 32 + j];
    }
    __syncthreads();

    const int stride = gridDim.x * 8;
    for (int n = blockIdx.x * 8 + grp; n < NN; n += stride) {
        float x0 = x[n * 3], x1 = x[n * 3 + 1], x2 = x[n * 3 + 2];
        float v[CC], acc[CC];
#pragma unroll
        for (int c = 0; c < CC; ++c) {
            v[c] = x0 * Breg[c][0] + x1 * Breg[c][1] + x2 * Breg[c][2];
            acc[c] = 0.f;
        }
        int e1 = offs[n + 1];
        for (int e = offs[n]; e < e1; ++e) {
            int r = csr_row[e];
            float r0 = x[r * 3], r1 = x[r * 3 + 1], r2 = x[r * 3 + 2];
#pragma unroll
            for (int c = 0; c < CC; ++c) {
                float u = hbreg[c] + r0 * Areg[c][0] + r1 * Areg[c][1] + r2 * Areg[c][2];
                acc[c] += fmaxf(u + v[c], 0.f);
            }
        }
        float s = 0.f;
#pragma unroll
        for (int c = 0; c < CC; ++c) {
#pragma unroll
            for (int k = 0; k < 32; ++k) {
                float a = __shfl(acc[c], k, 32);
                s += a * Mlds[c * 1024 + k * 32 + j];
            }
        }
        xw1[n * 32 + j] += s;
    }
}

// out[n][j] = dinv[n]*sum_{r in in(n)} xw[r][j]*dinv[r] + dinv[n]^2*xw[n][j]
__global__ void prop_csr(const int* __restrict__ offs, const int* __restrict__ csr_row,
                         const float* __restrict__ xw, const float* __restrict__ dinv,
                         float* __restrict__ out) {
    int grp = threadIdx.x >> 5, j = threadIdx.x & 31;
    int n = blockIdx.x * 8 + grp;
    if (n >= NN) return;
    int e0 = offs[n], e1 = offs[n + 1];
    float s0 = 0.f, s1 = 0.f;
    int e = e0;
    for (; e + 1 < e1; e += 2) {
        int r0 = csr_row[e], r1 = csr_row[e + 1];
        float d0 = dinv[r0], d1 = dinv[r1];
        s0 += xw[r0 * 32 + j] * d0;
        s1 += xw[r1 * 32 + j] * d1;
    }
    if (e < e1) { int r = csr_row[e]; s0 += xw[r * 32 + j] * dinv[r]; }
    float di = dinv[n];
    out[n * 32 + j] = di * (s0 + s1) + di * di * xw[n * 32 + j];
}

// xw2[n][j] = sum_k relu(h1raw[n][k] + g1b[k]) * g2W[k][j]
__global__ void xw2_kernel(const float* __restrict__ h1raw, const float* __restrict__ g1b,
                           const float* __restrict__ g2W, float* __restrict__ xw2) {
    int gid = blockIdx.x * 256 + threadIdx.x;
    if (gid >= NN * 32) return;
    int n = gid >> 5, j = gid & 31;
    float s = 0.f;
    for (int k = 0; k < 32; ++k) {
        float h = fmaxf(h1raw[n * 32 + k] + g1b[k], 0.0f);
        s += h * g2W[k * 32 + j];
    }
    xw2[gid] = s;
}

// segmented mean-pool: batch is sorted; each 32-lane group reduces 64 contiguous nodes
__global__ void pool_seg(const float* __restrict__ h2, const float* __restrict__ g2b,
                         const int* __restrict__ batch, float* __restrict__ pooled,
                         float* __restrict__ counts) {
    int grp = threadIdx.x >> 5, j = threadIdx.x & 31;
    int base = (blockIdx.x * 8 + grp) * 64;
    if (base >= NN) return;
    float bj = g2b[j];
    float acc = 0.f, cnt = 0.f;
    int curg = -1;
    int lim = base + 64;
    if (lim > NN) lim = NN;
    for (int n = base; n < lim; ++n) {
        int g = batch[n];
        if (g != curg) {
            if (curg >= 0) {
                atomicAdd(&pooled[curg * 32 + j], acc);
                if (j == 0) atomicAdd(&counts[curg], cnt);
            }
            curg = g; acc = 0.f; cnt = 0.f;
        }
        acc += fmaxf(h2[n * 32 + j] + bj, 0.f);
        cnt += 1.f;
    }
    if (curg >= 0) {
        atomicAdd(&pooled[curg * 32 + j], acc);
        if (j == 0) atomicAdd(&counts[curg], cnt);
    }
}

__global__ void final_kernel(const float* __restrict__ pooled, const float* __restrict__ counts,
                             const float* __restrict__ clsW, const float* __restrict__ clsb,
                             float* __restrict__ out) {
    int tid = threadIdx.x;
    if (tid >= GG * CC) return;
    int g = tid / CC, cc = tid % CC;
    float inv = 1.0f / fmaxf(counts[g], 1.0f);
    float s = clsb[cc];
    for (int j = 0; j < 32; ++j) s += (pooled[g * 32 + j] * inv) * clsW[j * CC + cc];
    out[g * CC + cc] = s;
}

extern "C" void kernel_launch(void* const* d_in, const int* in_sizes, int n_in,
                              void* d_out, int out_size, void* d_ws, size_t ws_size,
                              hipStream_t stream) {
    const float* x     = (const float*)d_in[0];
    const int*   ei    = (const int*)d_in[1];
    const int*   batch = (const int*)d_in[2];
    const float* fW    = (const float*)d_in[3];
    const float* fb    = (const float*)d_in[4];
    const float* W1    = (const float*)d_in[5];
    const float* b1    = (const float*)d_in[6];
    const float* W2    = (const float*)d_in[7];
    const float* b2    = (const float*)d_in[8];
    const float* g1W   = (const float*)d_in[9];
    const float* g1b   = (const float*)d_in[10];
    const float* g2W   = (const float*)d_in[11];
    const float* g2b   = (const float*)d_in[12];
    const float* clsW  = (const float*)d_in[13];
    const float* clsb  = (const float*)d_in[14];
    float* out = (float*)d_out;

    int*   ideg    = (int*)d_ws;
    int*   offs    = ideg + NN;
    int*   cursor  = offs + NN + 1;
    int*   csr_row = cursor + NN;
    float* dinv    = (float*)(csr_row + NE);
    float* tab     = dinv + NN;
    float* xw1     = tab + 16384;
    float* U       = xw1 + NN * 32;   // h1raw, later h2raw input slot reuse
    float* V       = U + NN * 32;     // xw2
    float* pooled  = V + NN * 32;
    float* counts  = pooled + GG * 32;

    const int nodeBlocks = (NN * 32 + 255) / 256;   // 12500
    const int edgeBlocks = (NE + 255) / 256;        // 6250
    const int grpBlocks  = (NN + 7) / 8;            // 12500

    zero_int<<<(NN + 255) / 256, 256, 0, stream>>>(ideg, NN);
    zero_f<<<(GG * 33 + 255) / 256, 256, 0, stream>>>(pooled, GG * 33);
    precompute_small<<<10, 1024, 0, stream>>>(fW, fb, W1, b1, W2, b2, g1W, tab);

    deg_int<<<edgeBlocks, 256, 0, stream>>>(ei, ideg);
    scan_kernel<<<1, 1024, 0, stream>>>(ideg, offs);
    prep_nodes<<<(NN + 255) / 256, 256, 0, stream>>>(ideg, offs, cursor, dinv);
    csr_fill<<<edgeBlocks, 256, 0, stream>>>(ei, cursor, csr_row);

    xw1_init<<<nodeBlocks, 256, 0, stream>>>(x, g1W, ideg, tab, xw1);
    edgeconv_fused<<<1563, 256, 0, stream>>>(x, offs, csr_row, tab, xw1);

    prop_csr<<<grpBlocks, 256, 0, stream>>>(offs, csr_row, xw1, dinv, U);   // h1raw
    xw2_kernel<<<nodeBlocks, 256, 0, stream>>>(U, g1b, g2W, V);             // xw2
    prop_csr<<<grpBlocks, 256, 0, stream>>>(offs, csr_row, V, dinv, xw1);   // h2raw -> xw1
    pool_seg<<<(NN + 511) / 512, 256, 0, stream>>>(xw1, g2b, batch, pooled, counts);
    final_kernel<<<1, 640, 0, stream>>>(pooled, counts, clsW, clsb, out);
}

// Round 3
// 1467.721 us; speedup vs baseline: 2.3600x; 1.0903x over previous
//
#include <hip/hip_runtime.h>

#define NN 100000
#define NE 1600000
#define HH 32
#define CC 10
#define GG 64

// ---------------- workspace layout ----------------
// float4 xe[NE]                       (at 0, 16B aligned: x0,x1,x2,dinv[row] per CSR slot)
// int    ideg[NN], offs[NN+1], cursor[NN], csr_row[NE]
// float  dinv[NN], tab[16384], xw1[NN*32], U[NN*32], V[NN*32], pooled[64*32], counts[64]
// tab: A[c][p][j] c*96+p*32+j ; B +960 ; hb[c][j] +1920 ; M[c][k][j] +2240 ; t[j] +12480

__global__ void zero_int(int* p, int n) {
    int i = blockIdx.x * 256 + threadIdx.x;
    if (i < n) p[i] = 0;
}

__global__ void zero_f(float* p, int n) {
    int i = blockIdx.x * 256 + threadIdx.x;
    if (i < n) p[i] = 0.0f;
}

__global__ void precompute_small(const float* __restrict__ fW, const float* __restrict__ fb,
                                 const float* __restrict__ W1, const float* __restrict__ b1,
                                 const float* __restrict__ W2, const float* __restrict__ b2,
                                 const float* __restrict__ g1W, float* __restrict__ tab) {
    int c = blockIdx.x;
    int k = threadIdx.x >> 5;
    int j = threadIdx.x & 31;
    float m = 0.f;
    for (int mm = 0; mm < 32; ++mm)
        m += W2[k * 32 + mm] * g1W[(3 + 32 * c + mm) * 32 + j];
    tab[2240 + c * 1024 + k * 32 + j] = m;

    if (k < 3) {
        float a = 0.f, b = 0.f;
        for (int i = 0; i < 32; ++i) {
            float w = fW[c * 96 + k * 32 + i];
            a += w * W1[i * 32 + j];
            b += w * W1[(32 + i) * 32 + j];
        }
        tab[c * 96 + k * 32 + j] = a;
        tab[960 + c * 96 + k * 32 + j] = b;
    } else if (k == 3) {
        float h = b1[j];
        for (int i = 0; i < 32; ++i)
            h += fb[c * 32 + i] * (W1[i * 32 + j] + W1[(32 + i) * 32 + j]);
        tab[1920 + c * 32 + j] = h;
    } else if (k == 4 && c == 0) {
        float t = 0.f;
        for (int cc2 = 0; cc2 < CC; ++cc2)
            for (int mm = 0; mm < 32; ++mm)
                t += b2[mm] * g1W[(3 + 32 * cc2 + mm) * 32 + j];
        tab[12480 + j] = t;
    }
}

__global__ void deg_int(const int* __restrict__ ei, int* __restrict__ ideg) {
    int e = blockIdx.x * 256 + threadIdx.x;
    if (e < NE) atomicAdd(&ideg[ei[NE + e]], 1);
}

__global__ void scan_kernel(const int* __restrict__ ideg, int* __restrict__ offs) {
    __shared__ int sums[1024];
    int tid = threadIdx.x;
    const int CH = (NN + 1023) / 1024;
    int base = tid * CH;
    int s = 0;
    for (int i = 0; i < CH; ++i) {
        int idx = base + i;
        if (idx < NN) s += ideg[idx];
    }
    sums[tid] = s;
    __syncthreads();
    for (int off = 1; off < 1024; off <<= 1) {
        int v = 0;
        if (tid >= off) v = sums[tid - off];
        __syncthreads();
        if (tid >= off) sums[tid] += v;
        __syncthreads();
    }
    int run = (tid == 0) ? 0 : sums[tid - 1];
    for (int i = 0; i < CH; ++i) {
        int idx = base + i;
        if (idx < NN) { offs[idx] = run; run += ideg[idx]; }
    }
    if (tid == 1023) offs[NN] = run;
}

__global__ void prep_nodes(const int* __restrict__ ideg, const int* __restrict__ offs,
                           int* __restrict__ cursor, float* __restrict__ dinv) {
    int n = blockIdx.x * 256 + threadIdx.x;
    if (n < NN) {
        cursor[n] = offs[n];
        dinv[n] = rsqrtf((float)ideg[n] + 1.0f);
    }
}

// CSR fill + edge payload: xe[pos] = (x[r].xyz, dinv[r])
__global__ void csr_fill(const int* __restrict__ ei, const float* __restrict__ x,
                         const float* __restrict__ dinv, int* __restrict__ cursor,
                         int* __restrict__ csr_row, float4* __restrict__ xe) {
    int e = blockIdx.x * 256 + threadIdx.x;
    if (e < NE) {
        int r = ei[e];
        int c = ei[NE + e];
        int pos = atomicAdd(&cursor[c], 1);
        csr_row[pos] = r;
        xe[pos] = make_float4(x[r * 3], x[r * 3 + 1], x[r * 3 + 2], dinv[r]);
    }
}

__global__ void xw1_init(const float* __restrict__ x, const float* __restrict__ g1W,
                         const int* __restrict__ ideg, const float* __restrict__ tab,
                         float* __restrict__ xw1) {
    int gid = blockIdx.x * 256 + threadIdx.x;
    if (gid >= NN * 32) return;
    int n = gid >> 5, j = gid & 31;
    float v = (float)ideg[n] * tab[12480 + j];
    v += x[n * 3 + 0] * g1W[0 * 32 + j];
    v += x[n * 3 + 1] * g1W[1 * 32 + j];
    v += x[n * 3 + 2] * g1W[2 * 32 + j];
    xw1[gid] = v;
}

// One node per wave64. Half-wave 0 -> classes 0-4, half-wave 1 -> classes 5-9.
// acc_c[j] = sum_e relu(va_c[j] + r.A_c[:,j]); then xw1[n][:] += sum_c acc_c @ M_c.
__global__ __launch_bounds__(256, 4) void edgeconv_fused(
    const float* __restrict__ x, const int* __restrict__ offs,
    const float4* __restrict__ xe, const float* __restrict__ tab,
    float* __restrict__ xw1) {
    __shared__ float Mlds[10240];
    for (int i = threadIdx.x; i < 10240; i += 256) Mlds[i] = tab[2240 + i];

    int lane = threadIdx.x & 63;
    int j = lane & 31;
    int half = lane >> 5;
    int c0 = half * 5;

    float A0[5], A1[5], A2[5], B0[5], B1[5], B2[5], hb[5];
#pragma unroll
    for (int i = 0; i < 5; ++i) {
        int cb = (c0 + i) * 96;
        A0[i] = tab[cb + j];       A1[i] = tab[cb + 32 + j];       A2[i] = tab[cb + 64 + j];
        B0[i] = tab[960 + cb + j]; B1[i] = tab[960 + cb + 32 + j]; B2[i] = tab[960 + cb + 64 + j];
        hb[i] = tab[1920 + (c0 + i) * 32 + j];
    }
    __syncthreads();

    int wid = blockIdx.x * 4 + (threadIdx.x >> 6);
    const int wstride = gridDim.x * 4;

    for (int n = wid; n < NN; n += wstride) {
        float x0 = x[n * 3], x1 = x[n * 3 + 1], x2 = x[n * 3 + 2];
        float va[5], acc[5];
#pragma unroll
        for (int i = 0; i < 5; ++i) {
            va[i] = hb[i] + x0 * B0[i] + x1 * B1[i] + x2 * B2[i];
            acc[i] = 0.f;
        }
        int e = offs[n], e1 = offs[n + 1];
        for (; e + 1 < e1; e += 2) {
            float4 p = xe[e];
            float4 q = xe[e + 1];
#pragma unroll
            for (int i = 0; i < 5; ++i)
                acc[i] += fmaxf(va[i] + p.x * A0[i] + p.y * A1[i] + p.z * A2[i], 0.f);
#pragma unroll
            for (int i = 0; i < 5; ++i)
                acc[i] += fmaxf(va[i] + q.x * A0[i] + q.y * A1[i] + q.z * A2[i], 0.f);
        }
        if (e < e1) {
            float4 p = xe[e];
#pragma unroll
            for (int i = 0; i < 5; ++i)
                acc[i] += fmaxf(va[i] + p.x * A0[i] + p.y * A1[i] + p.z * A2[i], 0.f);
        }
        // fold: each half does its 5 classes, then cross-half add
        float s = 0.f;
        int srcbase = lane & 32;
#pragma unroll
        for (int i = 0; i < 5; ++i) {
            const float* M = Mlds + (c0 + i) * 1024 + j;
#pragma unroll
            for (int k = 0; k < 32; ++k) {
                float a = __shfl(acc[i], srcbase | k, 64);
                s += a * M[k * 32];
            }
        }
        s += __shfl_xor(s, 32, 64);
        if (lane < 32) xw1[n * 32 + j] += s;
    }
}

// One node per wave64; half-waves take even/odd CSR slots. dinv[row] from xe.w.
__global__ __launch_bounds__(256, 4) void prop_wave(
    const int* __restrict__ offs, const int* __restrict__ csr_row,
    const float4* __restrict__ xe, const float* __restrict__ xw,
    const float* __restrict__ dinv, float* __restrict__ out) {
    int n = blockIdx.x * 4 + (threadIdx.x >> 6);
    if (n >= NN) return;
    int lane = threadIdx.x & 63;
    int j = lane & 31;
    int half = lane >> 5;
    int e0 = offs[n], e1 = offs[n + 1];
    float s0 = 0.f, s1 = 0.f;
    int e = e0 + half;
    for (; e + 2 < e1; e += 4) {
        int r0 = csr_row[e], r1 = csr_row[e + 2];
        float d0 = xe[e].w, d1 = xe[e + 2].w;
        s0 += xw[r0 * 32 + j] * d0;
        s1 += xw[r1 * 32 + j] * d1;
    }
    if (e < e1) {
        int r = csr_row[e];
        s0 += xw[r * 32 + j] * xe[e].w;
    }
    float s = s0 + s1;
    s += __shfl_xor(s, 32, 64);
    if (lane < 32) {
        float di = dinv[n];
        out[n * 32 + j] = di * s + di * di * xw[n * 32 + j];
    }
}

__global__ void xw2_kernel(const float* __restrict__ h1raw, const float* __restrict__ g1b,
                           const float* __restrict__ g2W, float* __restrict__ xw2) {
    int gid = blockIdx.x * 256 + threadIdx.x;
    if (gid >= NN * 32) return;
    int n = gid >> 5, j = gid & 31;
    float s = 0.f;
    for (int k = 0; k < 32; ++k) {
        float h = fmaxf(h1raw[n * 32 + k] + g1b[k], 0.0f);
        s += h * g2W[k * 32 + j];
    }
    xw2[gid] = s;
}

__global__ void pool_seg(const float* __restrict__ h2, const float* __restrict__ g2b,
                         const int* __restrict__ batch, float* __restrict__ pooled,
                         float* __restrict__ counts) {
    int grp = threadIdx.x >> 5, j = threadIdx.x & 31;
    int base = (blockIdx.x * 8 + grp) * 64;
    if (base >= NN) return;
    float bj = g2b[j];
    float acc = 0.f, cnt = 0.f;
    int curg = -1;
    int lim = base + 64;
    if (lim > NN) lim = NN;
    for (int n = base; n < lim; ++n) {
        int g = batch[n];
        if (g != curg) {
            if (curg >= 0) {
                atomicAdd(&pooled[curg * 32 + j], acc);
                if (j == 0) atomicAdd(&counts[curg], cnt);
            }
            curg = g; acc = 0.f; cnt = 0.f;
        }
        acc += fmaxf(h2[n * 32 + j] + bj, 0.f);
        cnt += 1.f;
    }
    if (curg >= 0) {
        atomicAdd(&pooled[curg * 32 + j], acc);
        if (j == 0) atomicAdd(&counts[curg], cnt);
    }
}

__global__ void final_kernel(const float* __restrict__ pooled, const float* __restrict__ counts,
                             const float* __restrict__ clsW, const float* __restrict__ clsb,
                             float* __restrict__ out) {
    int tid = threadIdx.x;
    if (tid >= GG * CC) return;
    int g = tid / CC, cc = tid % CC;
    float inv = 1.0f / fmaxf(counts[g], 1.0f);
    float s = clsb[cc];
    for (int j = 0; j < 32; ++j) s += (pooled[g * 32 + j] * inv) * clsW[j * CC + cc];
    out[g * CC + cc] = s;
}

extern "C" void kernel_launch(void* const* d_in, const int* in_sizes, int n_in,
                              void* d_out, int out_size, void* d_ws, size_t ws_size,
                              hipStream_t stream) {
    const float* x     = (const float*)d_in[0];
    const int*   ei    = (const int*)d_in[1];
    const int*   batch = (const int*)d_in[2];
    const float* fW    = (const float*)d_in[3];
    const float* fb    = (const float*)d_in[4];
    const float* W1    = (const float*)d_in[5];
    const float* b1    = (const float*)d_in[6];
    const float* W2    = (const float*)d_in[7];
    const float* b2    = (const float*)d_in[8];
    const float* g1W   = (const float*)d_in[9];
    const float* g1b   = (const float*)d_in[10];
    const float* g2W   = (const float*)d_in[11];
    const float* g2b   = (const float*)d_in[12];
    const float* clsW  = (const float*)d_in[13];
    const float* clsb  = (const float*)d_in[14];
    float* out = (float*)d_out;

    float4* xe     = (float4*)d_ws;                 // 16B-aligned at base
    int*    ideg   = (int*)(xe + NE);
    int*    offs   = ideg + NN;
    int*    cursor = offs + NN + 1;
    int*    csr_row= cursor + NN;
    float*  dinv   = (float*)(csr_row + NE);
    float*  tab    = dinv + NN;
    float*  xw1    = tab + 16384;
    float*  U      = xw1 + NN * 32;
    float*  V      = U + NN * 32;
    float*  pooled = V + NN * 32;
    float*  counts = pooled + GG * 32;

    const int nodeBlocks = (NN * 32 + 255) / 256;
    const int edgeBlocks = (NE + 255) / 256;
    const int waveBlocks = (NN + 3) / 4;            // one node per wave64, 4 waves/block

    zero_int<<<(NN + 255) / 256, 256, 0, stream>>>(ideg, NN);
    zero_f<<<(GG * 33 + 255) / 256, 256, 0, stream>>>(pooled, GG * 33);
    precompute_small<<<10, 1024, 0, stream>>>(fW, fb, W1, b1, W2, b2, g1W, tab);

    deg_int<<<edgeBlocks, 256, 0, stream>>>(ei, ideg);
    scan_kernel<<<1, 1024, 0, stream>>>(ideg, offs);
    prep_nodes<<<(NN + 255) / 256, 256, 0, stream>>>(ideg, offs, cursor, dinv);
    csr_fill<<<edgeBlocks, 256, 0, stream>>>(ei, x, dinv, cursor, csr_row, xe);

    xw1_init<<<nodeBlocks, 256, 0, stream>>>(x, g1W, ideg, tab, xw1);
    edgeconv_fused<<<1024, 256, 0, stream>>>(x, offs, xe, tab, xw1);

    prop_wave<<<waveBlocks, 256, 0, stream>>>(offs, csr_row, xe, xw1, dinv, U);   // h1raw
    xw2_kernel<<<nodeBlocks, 256, 0, stream>>>(U, g1b, g2W, V);                   // xw2
    prop_wave<<<waveBlocks, 256, 0, stream>>>(offs, csr_row, xe, V, dinv, xw1);   // h2raw
    pool_seg<<<(NN + 511) / 512, 256, 0, stream>>>(xw1, g2b, batch, pooled, counts);
    final_kernel<<<1, 640, 0, stream>>>(pooled, counts, clsW, clsb, out);
}

// Round 4
// 1369.675 us; speedup vs baseline: 2.5290x; 1.0716x over previous
//
#include <hip/hip_runtime.h>

#define NN 100000
#define NE 1600000
#define HH 32
#define CC 10
#define GG 64

// ---------------- workspace layout ----------------
// float4 xe[NE]                       (x0,x1,x2,dinv[row] per CSR slot)
// int    ideg[NN], offs[NN+1], cursor[NN], csr_row[NE]
// float  dinv[NN], tab[16384], xw1[NN*32], U[NN*32], V[NN*32], pooled[64*32], counts[64]
// tab: A[c][p][j] c*96+p*32+j ; B +960 ; hb[c][j] +1920 ; M[c][k][j] +2240 ; t[j] +12480

__global__ void zero_int(int* p, int n) {
    int i = blockIdx.x * 256 + threadIdx.x;
    if (i < n) p[i] = 0;
}

__global__ void zero_f(float* p, int n) {
    int i = blockIdx.x * 256 + threadIdx.x;
    if (i < n) p[i] = 0.0f;
}

__global__ void precompute_small(const float* __restrict__ fW, const float* __restrict__ fb,
                                 const float* __restrict__ W1, const float* __restrict__ b1,
                                 const float* __restrict__ W2, const float* __restrict__ b2,
                                 const float* __restrict__ g1W, float* __restrict__ tab) {
    int c = blockIdx.x;
    int k = threadIdx.x >> 5;
    int j = threadIdx.x & 31;
    float m = 0.f;
    for (int mm = 0; mm < 32; ++mm)
        m += W2[k * 32 + mm] * g1W[(3 + 32 * c + mm) * 32 + j];
    tab[2240 + c * 1024 + k * 32 + j] = m;

    if (k < 3) {
        float a = 0.f, b = 0.f;
        for (int i = 0; i < 32; ++i) {
            float w = fW[c * 96 + k * 32 + i];
            a += w * W1[i * 32 + j];
            b += w * W1[(32 + i) * 32 + j];
        }
        tab[c * 96 + k * 32 + j] = a;
        tab[960 + c * 96 + k * 32 + j] = b;
    } else if (k == 3) {
        float h = b1[j];
        for (int i = 0; i < 32; ++i)
            h += fb[c * 32 + i] * (W1[i * 32 + j] + W1[(32 + i) * 32 + j]);
        tab[1920 + c * 32 + j] = h;
    } else if (k == 4 && c == 0) {
        float t = 0.f;
        for (int cc2 = 0; cc2 < CC; ++cc2)
            for (int mm = 0; mm < 32; ++mm)
                t += b2[mm] * g1W[(3 + 32 * cc2 + mm) * 32 + j];
        tab[12480 + j] = t;
    }
}

__global__ void deg_int(const int* __restrict__ ei, int* __restrict__ ideg) {
    int e = blockIdx.x * 256 + threadIdx.x;
    if (e < NE) atomicAdd(&ideg[ei[NE + e]], 1);
}

__global__ void scan_kernel(const int* __restrict__ ideg, int* __restrict__ offs) {
    __shared__ int sums[1024];
    int tid = threadIdx.x;
    const int CH = (NN + 1023) / 1024;
    int base = tid * CH;
    int s = 0;
    for (int i = 0; i < CH; ++i) {
        int idx = base + i;
        if (idx < NN) s += ideg[idx];
    }
    sums[tid] = s;
    __syncthreads();
    for (int off = 1; off < 1024; off <<= 1) {
        int v = 0;
        if (tid >= off) v = sums[tid - off];
        __syncthreads();
        if (tid >= off) sums[tid] += v;
        __syncthreads();
    }
    int run = (tid == 0) ? 0 : sums[tid - 1];
    for (int i = 0; i < CH; ++i) {
        int idx = base + i;
        if (idx < NN) { offs[idx] = run; run += ideg[idx]; }
    }
    if (tid == 1023) offs[NN] = run;
}

__global__ void prep_nodes(const int* __restrict__ ideg, const int* __restrict__ offs,
                           int* __restrict__ cursor, float* __restrict__ dinv) {
    int n = blockIdx.x * 256 + threadIdx.x;
    if (n < NN) {
        cursor[n] = offs[n];
        dinv[n] = rsqrtf((float)ideg[n] + 1.0f);
    }
}

// CSR fill + edge payload: xe[pos] = (x[r].xyz, dinv[r])
__global__ void csr_fill(const int* __restrict__ ei, const float* __restrict__ x,
                         const float* __restrict__ dinv, int* __restrict__ cursor,
                         int* __restrict__ csr_row, float4* __restrict__ xe) {
    int e = blockIdx.x * 256 + threadIdx.x;
    if (e < NE) {
        int r = ei[e];
        int c = ei[NE + e];
        int pos = atomicAdd(&cursor[c], 1);
        csr_row[pos] = r;
        xe[pos] = make_float4(x[r * 3], x[r * 3 + 1], x[r * 3 + 2], dinv[r]);
    }
}

__global__ void xw1_init(const float* __restrict__ x, const float* __restrict__ g1W,
                         const int* __restrict__ ideg, const float* __restrict__ tab,
                         float* __restrict__ xw1) {
    int gid = blockIdx.x * 256 + threadIdx.x;
    if (gid >= NN * 32) return;
    int n = gid >> 5, j = gid & 31;
    float v = (float)ideg[n] * tab[12480 + j];
    v += x[n * 3 + 0] * g1W[0 * 32 + j];
    v += x[n * 3 + 1] * g1W[1 * 32 + j];
    v += x[n * 3 + 2] * g1W[2 * 32 + j];
    xw1[gid] = v;
}

__device__ __forceinline__ float bcast_lane(float v, int t) {
    return __uint_as_float(__builtin_amdgcn_readlane(__float_as_uint(v), (unsigned)t));
}

// One node per wave64. Half-wave 0 -> classes 0-4, half-wave 1 -> classes 5-9.
// Edge chunk: lane L loads xe[base+L] (coalesced, distinct addrs); edge t's
// features broadcast to all lanes via v_readlane (scalar pipe, no mem traffic).
__global__ __launch_bounds__(256, 4) void edgeconv_fused(
    const float* __restrict__ x, const int* __restrict__ offs,
    const float4* __restrict__ xe, const float* __restrict__ tab,
    float* __restrict__ xw1) {
    __shared__ float Mlds[10240];
    for (int i = threadIdx.x; i < 10240; i += 256) Mlds[i] = tab[2240 + i];

    int lane = threadIdx.x & 63;
    int j = lane & 31;
    int half = lane >> 5;
    int c0 = half * 5;

    float A0[5], A1[5], A2[5], B0[5], B1[5], B2[5], hb[5];
#pragma unroll
    for (int i = 0; i < 5; ++i) {
        int cb = (c0 + i) * 96;
        A0[i] = tab[cb + j];       A1[i] = tab[cb + 32 + j];       A2[i] = tab[cb + 64 + j];
        B0[i] = tab[960 + cb + j]; B1[i] = tab[960 + cb + 32 + j]; B2[i] = tab[960 + cb + 64 + j];
        hb[i] = tab[1920 + (c0 + i) * 32 + j];
    }
    __syncthreads();

    int wid = blockIdx.x * 4 + (threadIdx.x >> 6);
    const int wstride = gridDim.x * 4;

    for (int n = wid; n < NN; n += wstride) {
        float x0 = x[n * 3], x1 = x[n * 3 + 1], x2 = x[n * 3 + 2];
        float va[5], acc[5];
#pragma unroll
        for (int i = 0; i < 5; ++i) {
            va[i] = hb[i] + x0 * B0[i] + x1 * B1[i] + x2 * B2[i];
            acc[i] = 0.f;
        }
        int e0 = offs[n], e1 = offs[n + 1];
        for (int base = e0; base < e1; base += 64) {
            int ee = base + lane;
            float4 q = make_float4(0.f, 0.f, 0.f, 0.f);
            if (ee < e1) q = xe[ee];            // lane-parallel, coalesced
            int cnt = e1 - base;
            if (cnt > 64) cnt = 64;
            int t = 0;
            for (; t + 1 < cnt; t += 2) {
                float px0 = bcast_lane(q.x, t),     py0 = bcast_lane(q.y, t),     pz0 = bcast_lane(q.z, t);
                float px1 = bcast_lane(q.x, t + 1), py1 = bcast_lane(q.y, t + 1), pz1 = bcast_lane(q.z, t + 1);
#pragma unroll
                for (int i = 0; i < 5; ++i)
                    acc[i] += fmaxf(va[i] + px0 * A0[i] + py0 * A1[i] + pz0 * A2[i], 0.f);
#pragma unroll
                for (int i = 0; i < 5; ++i)
                    acc[i] += fmaxf(va[i] + px1 * A0[i] + py1 * A1[i] + pz1 * A2[i], 0.f);
            }
            if (t < cnt) {
                float px = bcast_lane(q.x, t), py = bcast_lane(q.y, t), pz = bcast_lane(q.z, t);
#pragma unroll
                for (int i = 0; i < 5; ++i)
                    acc[i] += fmaxf(va[i] + px * A0[i] + py * A1[i] + pz * A2[i], 0.f);
            }
        }
        // fold: each half does its 5 classes, then cross-half add
        float s = 0.f;
        int srcbase = lane & 32;
#pragma unroll
        for (int i = 0; i < 5; ++i) {
            const float* M = Mlds + (c0 + i) * 1024 + j;
#pragma unroll
            for (int k = 0; k < 32; ++k) {
                float a = __shfl(acc[i], srcbase | k, 64);
                s += a * M[k * 32];
            }
        }
        s += __shfl_xor(s, 32, 64);
        if (lane < 32) xw1[n * 32 + j] += s;
    }
}

// One node per wave64; half-waves take even/odd CSR slots. dinv[row] from xe.w.
__global__ __launch_bounds__(256, 4) void prop_wave(
    const int* __restrict__ offs, const int* __restrict__ csr_row,
    const float4* __restrict__ xe, const float* __restrict__ xw,
    const float* __restrict__ dinv, float* __restrict__ out) {
    int n = blockIdx.x * 4 + (threadIdx.x >> 6);
    if (n >= NN) return;
    int lane = threadIdx.x & 63;
    int j = lane & 31;
    int half = lane >> 5;
    int e0 = offs[n], e1 = offs[n + 1];
    float s0 = 0.f, s1 = 0.f;
    int e = e0 + half;
    for (; e + 2 < e1; e += 4) {
        int r0 = csr_row[e], r1 = csr_row[e + 2];
        float d0 = xe[e].w, d1 = xe[e + 2].w;
        s0 += xw[r0 * 32 + j] * d0;
        s1 += xw[r1 * 32 + j] * d1;
    }
    if (e < e1) {
        int r = csr_row[e];
        s0 += xw[r * 32 + j] * xe[e].w;
    }
    float s = s0 + s1;
    s += __shfl_xor(s, 32, 64);
    if (lane < 32) {
        float di = dinv[n];
        out[n * 32 + j] = di * s + di * di * xw[n * 32 + j];
    }
}

__global__ void xw2_kernel(const float* __restrict__ h1raw, const float* __restrict__ g1b,
                           const float* __restrict__ g2W, float* __restrict__ xw2) {
    int gid = blockIdx.x * 256 + threadIdx.x;
    if (gid >= NN * 32) return;
    int n = gid >> 5, j = gid & 31;
    float s = 0.f;
    for (int k = 0; k < 32; ++k) {
        float h = fmaxf(h1raw[n * 32 + k] + g1b[k], 0.0f);
        s += h * g2W[k * 32 + j];
    }
    xw2[gid] = s;
}

__global__ void pool_seg(const float* __restrict__ h2, const float* __restrict__ g2b,
                         const int* __restrict__ batch, float* __restrict__ pooled,
                         float* __restrict__ counts) {
    int grp = threadIdx.x >> 5, j = threadIdx.x & 31;
    int base = (blockIdx.x * 8 + grp) * 64;
    if (base >= NN) return;
    float bj = g2b[j];
    float acc = 0.f, cnt = 0.f;
    int curg = -1;
    int lim = base + 64;
    if (lim > NN) lim = NN;
    for (int n = base; n < lim; ++n) {
        int g = batch[n];
        if (g != curg) {
            if (curg >= 0) {
                atomicAdd(&pooled[curg * 32 + j], acc);
                if (j == 0) atomicAdd(&counts[curg], cnt);
            }
            curg = g; acc = 0.f; cnt = 0.f;
        }
        acc += fmaxf(h2[n * 32 + j] + bj, 0.f);
        cnt += 1.f;
    }
    if (curg >= 0) {
        atomicAdd(&pooled[curg * 32 + j], acc);
        if (j == 0) atomicAdd(&counts[curg], cnt);
    }
}

__global__ void final_kernel(const float* __restrict__ pooled, const float* __restrict__ counts,
                             const float* __restrict__ clsW, const float* __restrict__ clsb,
                             float* __restrict__ out) {
    int tid = threadIdx.x;
    if (tid >= GG * CC) return;
    int g = tid / CC, cc = tid % CC;
    float inv = 1.0f / fmaxf(counts[g], 1.0f);
    float s = clsb[cc];
    for (int j = 0; j < 32; ++j) s += (pooled[g * 32 + j] * inv) * clsW[j * CC + cc];
    out[g * CC + cc] = s;
}

extern "C" void kernel_launch(void* const* d_in, const int* in_sizes, int n_in,
                              void* d_out, int out_size, void* d_ws, size_t ws_size,
                              hipStream_t stream) {
    const float* x     = (const float*)d_in[0];
    const int*   ei    = (const int*)d_in[1];
    const int*   batch = (const int*)d_in[2];
    const float* fW    = (const float*)d_in[3];
    const float* fb    = (const float*)d_in[4];
    const float* W1    = (const float*)d_in[5];
    const float* b1    = (const float*)d_in[6];
    const float* W2    = (const float*)d_in[7];
    const float* b2    = (const float*)d_in[8];
    const float* g1W   = (const float*)d_in[9];
    const float* g1b   = (const float*)d_in[10];
    const float* g2W   = (const float*)d_in[11];
    const float* g2b   = (const float*)d_in[12];
    const float* clsW  = (const float*)d_in[13];
    const float* clsb  = (const float*)d_in[14];
    float* out = (float*)d_out;

    float4* xe     = (float4*)d_ws;
    int*    ideg   = (int*)(xe + NE);
    int*    offs   = ideg + NN;
    int*    cursor = offs + NN + 1;
    int*    csr_row= cursor + NN;
    float*  dinv   = (float*)(csr_row + NE);
    float*  tab    = dinv + NN;
    float*  xw1    = tab + 16384;
    float*  U      = xw1 + NN * 32;
    float*  V      = U + NN * 32;
    float*  pooled = V + NN * 32;
    float*  counts = pooled + GG * 32;

    const int nodeBlocks = (NN * 32 + 255) / 256;
    const int edgeBlocks = (NE + 255) / 256;
    const int waveBlocks = (NN + 3) / 4;

    zero_int<<<(NN + 255) / 256, 256, 0, stream>>>(ideg, NN);
    zero_f<<<(GG * 33 + 255) / 256, 256, 0, stream>>>(pooled, GG * 33);
    precompute_small<<<10, 1024, 0, stream>>>(fW, fb, W1, b1, W2, b2, g1W, tab);

    deg_int<<<edgeBlocks, 256, 0, stream>>>(ei, ideg);
    scan_kernel<<<1, 1024, 0, stream>>>(ideg, offs);
    prep_nodes<<<(NN + 255) / 256, 256, 0, stream>>>(ideg, offs, cursor, dinv);
    csr_fill<<<edgeBlocks, 256, 0, stream>>>(ei, x, dinv, cursor, csr_row, xe);

    xw1_init<<<nodeBlocks, 256, 0, stream>>>(x, g1W, ideg, tab, xw1);
    edgeconv_fused<<<1024, 256, 0, stream>>>(x, offs, xe, tab, xw1);

    prop_wave<<<waveBlocks, 256, 0, stream>>>(offs, csr_row, xe, xw1, dinv, U);   // h1raw
    xw2_kernel<<<nodeBlocks, 256, 0, stream>>>(U, g1b, g2W, V);                   // xw2
    prop_wave<<<waveBlocks, 256, 0, stream>>>(offs, csr_row, xe, V, dinv, xw1);   // h2raw
    pool_seg<<<(NN + 511) / 512, 256, 0, stream>>>(xw1, g2b, batch, pooled, counts);
    final_kernel<<<1, 640, 0, stream>>>(pooled, counts, clsW, clsb, out);
}

// Round 5
// 863.889 us; speedup vs baseline: 4.0096x; 1.5855x over previous
//
#include <hip/hip_runtime.h>

#define NN 100000
#define NE 1600000
#define HH 32
#define CC 10
#define GG 64
#define STRIP 25000

typedef _Float16 half8 __attribute__((ext_vector_type(8)));
typedef _Float16 half2v __attribute__((ext_vector_type(2)));
typedef float f32x4 __attribute__((ext_vector_type(4)));

// ---------------- workspace layout ----------------
// float4 xe[NE]; uint agg[STRIP*320]; int2 rd[NE]; int ideg[NN], offs[NN+1], cursor[NN];
// float dinv[NN], tab[16384]; _Float16 Mfrag[20480]; float xw1[NN*32], U, V, pooled, counts
// tab: A[c][p][j] c*96+p*32+j ; B +960 ; hb[c][j] +1920 ; Mflat[320][32] +2240 ; t[j] +12480

__global__ void zero_int(int* p, int n) {
    int i = blockIdx.x * 256 + threadIdx.x;
    if (i < n) p[i] = 0;
}

__global__ void zero_f(float* p, int n) {
    int i = blockIdx.x * 256 + threadIdx.x;
    if (i < n) p[i] = 0.0f;
}

__global__ void precompute_small(const float* __restrict__ fW, const float* __restrict__ fb,
                                 const float* __restrict__ W1, const float* __restrict__ b1,
                                 const float* __restrict__ W2, const float* __restrict__ b2,
                                 const float* __restrict__ g1W, float* __restrict__ tab) {
    int c = blockIdx.x;
    int k = threadIdx.x >> 5;
    int j = threadIdx.x & 31;
    float m = 0.f;
    for (int mm = 0; mm < 32; ++mm)
        m += W2[k * 32 + mm] * g1W[(3 + 32 * c + mm) * 32 + j];
    tab[2240 + c * 1024 + k * 32 + j] = m;

    if (k < 3) {
        float a = 0.f, b = 0.f;
        for (int i = 0; i < 32; ++i) {
            float w = fW[c * 96 + k * 32 + i];
            a += w * W1[i * 32 + j];
            b += w * W1[(32 + i) * 32 + j];
        }
        tab[c * 96 + k * 32 + j] = a;
        tab[960 + c * 96 + k * 32 + j] = b;
    } else if (k == 3) {
        float h = b1[j];
        for (int i = 0; i < 32; ++i)
            h += fb[c * 32 + i] * (W1[i * 32 + j] + W1[(32 + i) * 32 + j]);
        tab[1920 + c * 32 + j] = h;
    } else if (k == 4 && c == 0) {
        float t = 0.f;
        for (int cc2 = 0; cc2 < CC; ++cc2)
            for (int mm = 0; mm < 32; ++mm)
                t += b2[mm] * g1W[(3 + 32 * cc2 + mm) * 32 + j];
        tab[12480 + j] = t;
    }
}

// Pre-swizzle Mflat[320][32] into MFMA B-fragment order, fp16 hi/lo planes.
// set = (kc*2+jt)*2+p ; lane l holds B[k=kc*32+(l>>4)*8+i][j=jt*16+(l&15)]
__global__ void mfrag_kernel(const float* __restrict__ tab, _Float16* __restrict__ Mfrag) {
    int gid = blockIdx.x * 256 + threadIdx.x;   // [0, 2560)
    if (gid >= 2560) return;
    int set = gid >> 6, l = gid & 63;
    int p = set & 1, jt = (set >> 1) & 1, kc = set >> 2;
    int j = jt * 16 + (l & 15);
    int kbase = kc * 32 + (l >> 4) * 8;
#pragma unroll
    for (int i = 0; i < 8; ++i) {
        float v = tab[2240 + (kbase + i) * 32 + j];
        _Float16 hi = (_Float16)v;
        Mfrag[gid * 8 + i] = p ? (_Float16)(v - (float)hi) : hi;
    }
}

__global__ void deg_int(const int* __restrict__ ei, int* __restrict__ ideg) {
    int e = blockIdx.x * 256 + threadIdx.x;
    if (e < NE) atomicAdd(&ideg[ei[NE + e]], 1);
}

__global__ void scan_kernel(const int* __restrict__ ideg, int* __restrict__ offs) {
    __shared__ int sums[1024];
    int tid = threadIdx.x;
    const int CH = (NN + 1023) / 1024;
    int base = tid * CH;
    int s = 0;
    for (int i = 0; i < CH; ++i) {
        int idx = base + i;
        if (idx < NN) s += ideg[idx];
    }
    sums[tid] = s;
    __syncthreads();
    for (int off = 1; off < 1024; off <<= 1) {
        int v = 0;
        if (tid >= off) v = sums[tid - off];
        __syncthreads();
        if (tid >= off) sums[tid] += v;
        __syncthreads();
    }
    int run = (tid == 0) ? 0 : sums[tid - 1];
    for (int i = 0; i < CH; ++i) {
        int idx = base + i;
        if (idx < NN) { offs[idx] = run; run += ideg[idx]; }
    }
    if (tid == 1023) offs[NN] = run;
}

__global__ void prep_nodes(const int* __restrict__ ideg, const int* __restrict__ offs,
                           int* __restrict__ cursor, float* __restrict__ dinv) {
    int n = blockIdx.x * 256 + threadIdx.x;
    if (n < NN) {
        cursor[n] = offs[n];
        dinv[n] = rsqrtf((float)ideg[n] + 1.0f);
    }
}

// CSR fill: xe[pos]=(x[r].xyz, dinv[r]) for edgeconv; rd[pos]=(r, dinv[r]) for prop
__global__ void csr_fill(const int* __restrict__ ei, const float* __restrict__ x,
                         const float* __restrict__ dinv, int* __restrict__ cursor,
                         int2* __restrict__ rd, float4* __restrict__ xe) {
    int e = blockIdx.x * 256 + threadIdx.x;
    if (e < NE) {
        int r = ei[e];
        int c = ei[NE + e];
        float dr = dinv[r];
        int pos = atomicAdd(&cursor[c], 1);
        rd[pos] = make_int2(r, __float_as_int(dr));
        xe[pos] = make_float4(x[r * 3], x[r * 3 + 1], x[r * 3 + 2], dr);
    }
}

__global__ void xw1_init(const float* __restrict__ x, const float* __restrict__ g1W,
                         const int* __restrict__ ideg, const float* __restrict__ tab,
                         float* __restrict__ xw1) {
    int gid = blockIdx.x * 256 + threadIdx.x;
    if (gid >= NN * 32) return;
    int n = gid >> 5, j = gid & 31;
    float v = (float)ideg[n] * tab[12480 + j];
    v += x[n * 3 + 0] * g1W[0 * 32 + j];
    v += x[n * 3 + 1] * g1W[1 * 32 + j];
    v += x[n * 3 + 2] * g1W[2 * 32 + j];
    xw1[gid] = v;
}

__device__ __forceinline__ float bcast_lane(float v, int t) {
    return __uint_as_float(__builtin_amdgcn_readlane(__float_as_uint(v), (unsigned)t));
}

// Edge phase only: one node per wave, halves take classes 0-4 / 5-9.
// Writes agg[n-n_start][c*32+j] as packed (fp16 hi | fp16 lo) u32.
__global__ __launch_bounds__(256, 8) void edgeconv_fused(
    const float* __restrict__ x, const int* __restrict__ offs,
    const float4* __restrict__ xe, const float* __restrict__ tab,
    unsigned int* __restrict__ agg, int n_start, int n_end) {
    int lane = threadIdx.x & 63;
    int j = lane & 31;
    int half = lane >> 5;
    int c0 = half * 5;

    float A0[5], A1[5], A2[5], B0[5], B1[5], B2[5], hb[5];
#pragma unroll
    for (int i = 0; i < 5; ++i) {
        int cb = (c0 + i) * 96;
        A0[i] = tab[cb + j];       A1[i] = tab[cb + 32 + j];       A2[i] = tab[cb + 64 + j];
        B0[i] = tab[960 + cb + j]; B1[i] = tab[960 + cb + 32 + j]; B2[i] = tab[960 + cb + 64 + j];
        hb[i] = tab[1920 + (c0 + i) * 32 + j];
    }

    int wid = blockIdx.x * 4 + (threadIdx.x >> 6);
    const int wstride = gridDim.x * 4;

    for (int n = n_start + wid; n < n_end; n += wstride) {
        float x0 = x[n * 3], x1 = x[n * 3 + 1], x2 = x[n * 3 + 2];
        float va[5], acc[5];
#pragma unroll
        for (int i = 0; i < 5; ++i) {
            va[i] = hb[i] + x0 * B0[i] + x1 * B1[i] + x2 * B2[i];
            acc[i] = 0.f;
        }
        int e0 = offs[n], e1 = offs[n + 1];
        for (int base = e0; base < e1; base += 64) {
            int ee = base + lane;
            float4 q = make_float4(0.f, 0.f, 0.f, 0.f);
            if (ee < e1) q = xe[ee];
            int cnt = e1 - base;
            if (cnt > 64) cnt = 64;
            int t = 0;
            for (; t + 1 < cnt; t += 2) {
                float px0 = bcast_lane(q.x, t),     py0 = bcast_lane(q.y, t),     pz0 = bcast_lane(q.z, t);
                float px1 = bcast_lane(q.x, t + 1), py1 = bcast_lane(q.y, t + 1), pz1 = bcast_lane(q.z, t + 1);
#pragma unroll
                for (int i = 0; i < 5; ++i)
                    acc[i] += fmaxf(va[i] + px0 * A0[i] + py0 * A1[i] + pz0 * A2[i], 0.f);
#pragma unroll
                for (int i = 0; i < 5; ++i)
                    acc[i] += fmaxf(va[i] + px1 * A0[i] + py1 * A1[i] + pz1 * A2[i], 0.f);
            }
            if (t < cnt) {
                float px = bcast_lane(q.x, t), py = bcast_lane(q.y, t), pz = bcast_lane(q.z, t);
#pragma unroll
                for (int i = 0; i < 5; ++i)
                    acc[i] += fmaxf(va[i] + px * A0[i] + py * A1[i] + pz * A2[i], 0.f);
            }
        }
        unsigned int* arow = agg + (unsigned)(n - n_start) * 320 + half * 160 + j;
#pragma unroll
        for (int i = 0; i < 5; ++i) {
            float a = acc[i];
            _Float16 hi = (_Float16)a;
            _Float16 lo = (_Float16)(a - (float)hi);
            half2v pr = {hi, lo};
            arow[i * 32] = __builtin_bit_cast(unsigned int, pr);
        }
    }
}

// Fold via MFMA: xw1[n][:] += agg[n][0:320] @ Mflat[320][32], 16 nodes/wave.
// fp16 split-pair: D = ah*mh + al*mh + ah*ml  (error ~2^-22)
__global__ __launch_bounds__(256) void fold_mfma(
    const unsigned int* __restrict__ agg, const _Float16* __restrict__ MfragG,
    float* __restrict__ xw1, int n_start, int n_end) {
    __shared__ _Float16 Mf[20480];
    {
        const uint4* src = (const uint4*)MfragG;
        uint4* dst = (uint4*)Mf;
        for (int i = threadIdx.x; i < 2560; i += 256) dst[i] = src[i];
    }
    __syncthreads();

    int wave = blockIdx.x * 4 + (threadIdx.x >> 6);
    int lane = threadIdx.x & 63;
    int n0 = n_start + wave * 16;
    if (n0 >= n_end) return;

    int m = lane & 15, q = lane >> 4;
    int arow_n = n0 + m;
    bool rowok = arow_n < n_end;
    const unsigned int* arow = agg + (unsigned)(arow_n - n_start) * 320 + q * 8;

    const half8* mf = (const half8*)Mf;
    f32x4 acc0 = {0.f, 0.f, 0.f, 0.f};
    f32x4 acc1 = {0.f, 0.f, 0.f, 0.f};

    for (int kc = 0; kc < 10; ++kc) {
        half8 ah, al;
        if (rowok) {
            uint4 w0 = *(const uint4*)(arow + kc * 32);
            uint4 w1 = *(const uint4*)(arow + kc * 32 + 4);
            unsigned int w[8] = {w0.x, w0.y, w0.z, w0.w, w1.x, w1.y, w1.z, w1.w};
#pragma unroll
            for (int i = 0; i < 8; ++i) {
                half2v pr = __builtin_bit_cast(half2v, w[i]);
                ah[i] = pr.x;
                al[i] = pr.y;
            }
        } else {
#pragma unroll
            for (int i = 0; i < 8; ++i) { ah[i] = (_Float16)0.f; al[i] = (_Float16)0.f; }
        }
        half8 bh0 = mf[((kc * 2 + 0) * 2 + 0) * 64 + lane];
        half8 bl0 = mf[((kc * 2 + 0) * 2 + 1) * 64 + lane];
        half8 bh1 = mf[((kc * 2 + 1) * 2 + 0) * 64 + lane];
        half8 bl1 = mf[((kc * 2 + 1) * 2 + 1) * 64 + lane];
        acc0 = __builtin_amdgcn_mfma_f32_16x16x32_f16(ah, bh0, acc0, 0, 0, 0);
        acc0 = __builtin_amdgcn_mfma_f32_16x16x32_f16(al, bh0, acc0, 0, 0, 0);
        acc0 = __builtin_amdgcn_mfma_f32_16x16x32_f16(ah, bl0, acc0, 0, 0, 0);
        acc1 = __builtin_amdgcn_mfma_f32_16x16x32_f16(ah, bh1, acc1, 0, 0, 0);
        acc1 = __builtin_amdgcn_mfma_f32_16x16x32_f16(al, bh1, acc1, 0, 0, 0);
        acc1 = __builtin_amdgcn_mfma_f32_16x16x32_f16(ah, bl1, acc1, 0, 0, 0);
    }

    // C/D layout: col = lane&15 (j within tile), row = q*4 + r (node within 16)
    int jcol = lane & 15;
#pragma unroll
    for (int r = 0; r < 4; ++r) {
        int node = n0 + q * 4 + r;
        if (node < n_end) {
            xw1[node * 32 + jcol] += acc0[r];
            xw1[node * 32 + 16 + jcol] += acc1[r];
        }
    }
}

// One node per wave64; half-waves take even/odd CSR slots; (r,dinv_r) one b64 load.
__global__ __launch_bounds__(256, 4) void prop_wave(
    const int* __restrict__ offs, const int2* __restrict__ rd,
    const float* __restrict__ xw, const float* __restrict__ dinv,
    float* __restrict__ out) {
    int n = blockIdx.x * 4 + (threadIdx.x >> 6);
    if (n >= NN) return;
    int lane = threadIdx.x & 63;
    int j = lane & 31;
    int half = lane >> 5;
    int e0 = offs[n], e1 = offs[n + 1];
    float s0 = 0.f, s1 = 0.f;
    int e = e0 + half;
    for (; e + 2 < e1; e += 4) {
        int2 p0 = rd[e];
        int2 p1 = rd[e + 2];
        s0 += xw[p0.x * 32 + j] * __int_as_float(p0.y);
        s1 += xw[p1.x * 32 + j] * __int_as_float(p1.y);
    }
    if (e < e1) {
        int2 p = rd[e];
        s0 += xw[p.x * 32 + j] * __int_as_float(p.y);
    }
    float s = s0 + s1;
    s += __shfl_xor(s, 32, 64);
    if (lane < 32) {
        float di = dinv[n];
        out[n * 32 + j] = di * s + di * di * xw[n * 32 + j];
    }
}

__global__ void xw2_kernel(const float* __restrict__ h1raw, const float* __restrict__ g1b,
                           const float* __restrict__ g2W, float* __restrict__ xw2) {
    int gid = blockIdx.x * 256 + threadIdx.x;
    if (gid >= NN * 32) return;
    int n = gid >> 5, j = gid & 31;
    float s = 0.f;
    for (int k = 0; k < 32; ++k) {
        float h = fmaxf(h1raw[n * 32 + k] + g1b[k], 0.0f);
        s += h * g2W[k * 32 + j];
    }
    xw2[gid] = s;
}

__global__ void pool_seg(const float* __restrict__ h2, const float* __restrict__ g2b,
                         const int* __restrict__ batch, float* __restrict__ pooled,
                         float* __restrict__ counts) {
    int grp = threadIdx.x >> 5, j = threadIdx.x & 31;
    int base = (blockIdx.x * 8 + grp) * 64;
    if (base >= NN) return;
    float bj = g2b[j];
    float acc = 0.f, cnt = 0.f;
    int curg = -1;
    int lim = base + 64;
    if (lim > NN) lim = NN;
    for (int n = base; n < lim; ++n) {
        int g = batch[n];
        if (g != curg) {
            if (curg >= 0) {
                atomicAdd(&pooled[curg * 32 + j], acc);
                if (j == 0) atomicAdd(&counts[curg], cnt);
            }
            curg = g; acc = 0.f; cnt = 0.f;
        }
        acc += fmaxf(h2[n * 32 + j] + bj, 0.f);
        cnt += 1.f;
    }
    if (curg >= 0) {
        atomicAdd(&pooled[curg * 32 + j], acc);
        if (j == 0) atomicAdd(&counts[curg], cnt);
    }
}

__global__ void final_kernel(const float* __restrict__ pooled, const float* __restrict__ counts,
                             const float* __restrict__ clsW, const float* __restrict__ clsb,
                             float* __restrict__ out) {
    int tid = threadIdx.x;
    if (tid >= GG * CC) return;
    int g = tid / CC, cc = tid % CC;
    float inv = 1.0f / fmaxf(counts[g], 1.0f);
    float s = clsb[cc];
    for (int j = 0; j < 32; ++j) s += (pooled[g * 32 + j] * inv) * clsW[j * CC + cc];
    out[g * CC + cc] = s;
}

extern "C" void kernel_launch(void* const* d_in, const int* in_sizes, int n_in,
                              void* d_out, int out_size, void* d_ws, size_t ws_size,
                              hipStream_t stream) {
    const float* x     = (const float*)d_in[0];
    const int*   ei    = (const int*)d_in[1];
    const int*   batch = (const int*)d_in[2];
    const float* fW    = (const float*)d_in[3];
    const float* fb    = (const float*)d_in[4];
    const float* W1    = (const float*)d_in[5];
    const float* b1    = (const float*)d_in[6];
    const float* W2    = (const float*)d_in[7];
    const float* b2    = (const float*)d_in[8];
    const float* g1W   = (const float*)d_in[9];
    const float* g1b   = (const float*)d_in[10];
    const float* g2W   = (const float*)d_in[11];
    const float* g2b   = (const float*)d_in[12];
    const float* clsW  = (const float*)d_in[13];
    const float* clsb  = (const float*)d_in[14];
    float* out = (float*)d_out;

    float4*       xe     = (float4*)d_ws;
    unsigned int* agg    = (unsigned int*)(xe + NE);           // STRIP*320 u32 = 32 MB
    int2*         rd     = (int2*)(agg + (size_t)STRIP * 320);
    int*          ideg   = (int*)(rd + NE);
    int*          offs   = ideg + NN;
    int*          cursor = offs + NN + 1;
    float*        dinv   = (float*)(cursor + NN);
    float*        tab    = dinv + NN;
    _Float16*     Mfrag  = (_Float16*)(tab + 16384);           // 20480 halfs
    float*        xw1    = tab + 16384 + 10240;
    float*        U      = xw1 + NN * 32;
    float*        V      = U + NN * 32;
    float*        pooled = V + NN * 32;
    float*        counts = pooled + GG * 32;

    const int nodeBlocks = (NN * 32 + 255) / 256;
    const int edgeBlocks = (NE + 255) / 256;
    const int waveBlocks = (NN + 3) / 4;

    zero_int<<<(NN + 255) / 256, 256, 0, stream>>>(ideg, NN);
    zero_f<<<(GG * 33 + 255) / 256, 256, 0, stream>>>(pooled, GG * 33);
    precompute_small<<<10, 1024, 0, stream>>>(fW, fb, W1, b1, W2, b2, g1W, tab);
    mfrag_kernel<<<10, 256, 0, stream>>>(tab, Mfrag);

    deg_int<<<edgeBlocks, 256, 0, stream>>>(ei, ideg);
    scan_kernel<<<1, 1024, 0, stream>>>(ideg, offs);
    prep_nodes<<<(NN + 255) / 256, 256, 0, stream>>>(ideg, offs, cursor, dinv);
    csr_fill<<<edgeBlocks, 256, 0, stream>>>(ei, x, dinv, cursor, rd, xe);

    xw1_init<<<nodeBlocks, 256, 0, stream>>>(x, g1W, ideg, tab, xw1);

    for (int s = 0; s < NN / STRIP; ++s) {
        int ns = s * STRIP, ne2 = ns + STRIP;
        edgeconv_fused<<<640, 256, 0, stream>>>(x, offs, xe, tab, agg, ns, ne2);
        int foldWaves = (STRIP + 15) / 16;
        fold_mfma<<<(foldWaves + 3) / 4, 256, 0, stream>>>(agg, Mfrag, xw1, ns, ne2);
    }

    prop_wave<<<waveBlocks, 256, 0, stream>>>(offs, rd, xw1, dinv, U);   // h1raw
    xw2_kernel<<<nodeBlocks, 256, 0, stream>>>(U, g1b, g2W, V);          // xw2
    prop_wave<<<waveBlocks, 256, 0, stream>>>(offs, rd, V, dinv, xw1);   // h2raw
    pool_seg<<<(NN + 511) / 512, 256, 0, stream>>>(xw1, g2b, batch, pooled, counts);
    final_kernel<<<1, 640, 0, stream>>>(pooled, counts, clsW, clsb, out);
}

// Round 6
// 682.653 us; speedup vs baseline: 5.0741x; 1.2655x over previous
//
#include <hip/hip_runtime.h>

#define NN 100000
#define NE 1600000
#define HH 32
#define CC 10
#define GG 64
#define STRIP 25000
#define SBLK ((NN + 255) / 256)   // 391 scan blocks

typedef _Float16 half8 __attribute__((ext_vector_type(8)));
typedef _Float16 half2v __attribute__((ext_vector_type(2)));
typedef float f32x4 __attribute__((ext_vector_type(4)));

// ---------------- workspace layout ----------------
// float4 xe[NE]; uint agg[STRIP*320]; int2 rd[NE]; int ideg[NN], offs[NN+1], cursor[NN];
// int bsum[512]; float dinv[NN], tab[16384]; _Float16 Mfrag[20480];
// float xw1[NN*32], U, V, pooled, counts
// tab: A[c][p][j] c*96+p*32+j ; B +960 ; hb[c][j] +1920 ; Mflat[320][32] +2240 ; t[j] +12480

__global__ void zero_int(int* p, int n) {
    int i = blockIdx.x * 256 + threadIdx.x;
    if (i < n) p[i] = 0;
}

__global__ void zero_f(float* p, int n) {
    int i = blockIdx.x * 256 + threadIdx.x;
    if (i < n) p[i] = 0.0f;
}

__global__ void precompute_small(const float* __restrict__ fW, const float* __restrict__ fb,
                                 const float* __restrict__ W1, const float* __restrict__ b1,
                                 const float* __restrict__ W2, const float* __restrict__ b2,
                                 const float* __restrict__ g1W, float* __restrict__ tab) {
    int c = blockIdx.x;
    int k = threadIdx.x >> 5;
    int j = threadIdx.x & 31;
    float m = 0.f;
    for (int mm = 0; mm < 32; ++mm)
        m += W2[k * 32 + mm] * g1W[(3 + 32 * c + mm) * 32 + j];
    tab[2240 + c * 1024 + k * 32 + j] = m;

    if (k < 3) {
        float a = 0.f, b = 0.f;
        for (int i = 0; i < 32; ++i) {
            float w = fW[c * 96 + k * 32 + i];
            a += w * W1[i * 32 + j];
            b += w * W1[(32 + i) * 32 + j];
        }
        tab[c * 96 + k * 32 + j] = a;
        tab[960 + c * 96 + k * 32 + j] = b;
    } else if (k == 3) {
        float h = b1[j];
        for (int i = 0; i < 32; ++i)
            h += fb[c * 32 + i] * (W1[i * 32 + j] + W1[(32 + i) * 32 + j]);
        tab[1920 + c * 32 + j] = h;
    } else if (k == 4 && c == 0) {
        float t = 0.f;
        for (int cc2 = 0; cc2 < CC; ++cc2)
            for (int mm = 0; mm < 32; ++mm)
                t += b2[mm] * g1W[(3 + 32 * cc2 + mm) * 32 + j];
        tab[12480 + j] = t;
    }
}

// Pre-swizzle Mflat[320][32] into MFMA B-fragment order, fp16 hi/lo planes.
__global__ void mfrag_kernel(const float* __restrict__ tab, _Float16* __restrict__ Mfrag) {
    int gid = blockIdx.x * 256 + threadIdx.x;   // [0, 2560)
    if (gid >= 2560) return;
    int set = gid >> 6, l = gid & 63;
    int p = set & 1, jt = (set >> 1) & 1, kc = set >> 2;
    int j = jt * 16 + (l & 15);
    int kbase = kc * 32 + (l >> 4) * 8;
#pragma unroll
    for (int i = 0; i < 8; ++i) {
        float v = tab[2240 + (kbase + i) * 32 + j];
        _Float16 hi = (_Float16)v;
        Mfrag[gid * 8 + i] = p ? (_Float16)(v - (float)hi) : hi;
    }
}

__global__ void deg_int(const int* __restrict__ ei, int* __restrict__ ideg) {
    int e = blockIdx.x * 256 + threadIdx.x;
    if (e < NE) atomicAdd(&ideg[ei[NE + e]], 1);
}

// -------- hierarchical scan: 391 blocks -> 1 block -> 391 blocks --------
__global__ void scan_phase1(const int* __restrict__ ideg, int* __restrict__ bsum) {
    __shared__ int sh[256];
    int b = blockIdx.x, t = threadIdx.x;
    int i = b * 256 + t;
    sh[t] = (i < NN) ? ideg[i] : 0;
    __syncthreads();
    for (int off = 128; off > 0; off >>= 1) {
        if (t < off) sh[t] += sh[t + off];
        __syncthreads();
    }
    if (t == 0) bsum[b] = sh[0];
}

__global__ void scan_phase2(int* __restrict__ bsum) {
    __shared__ int sh[512];
    int t = threadIdx.x;
    int v = (t < SBLK) ? bsum[t] : 0;
    sh[t] = v;
    __syncthreads();
    for (int off = 1; off < 512; off <<= 1) {
        int add = (t >= off) ? sh[t - off] : 0;
        __syncthreads();
        sh[t] += add;
        __syncthreads();
    }
    if (t < SBLK) bsum[t] = sh[t] - v;   // exclusive
}

// phase3: per-block exclusive scan + block offset; also fills cursor & dinv
__global__ void scan_phase3(const int* __restrict__ ideg, const int* __restrict__ bsum,
                            int* __restrict__ offs, int* __restrict__ cursor,
                            float* __restrict__ dinv) {
    __shared__ int sh[256];
    int b = blockIdx.x, t = threadIdx.x;
    int i = b * 256 + t;
    int v = (i < NN) ? ideg[i] : 0;
    sh[t] = v;
    __syncthreads();
    for (int off = 1; off < 256; off <<= 1) {
        int add = (t >= off) ? sh[t - off] : 0;
        __syncthreads();
        sh[t] += add;
        __syncthreads();
    }
    int excl = sh[t] - v + bsum[b];
    if (i < NN) {
        offs[i] = excl;
        cursor[i] = excl;
        dinv[i] = rsqrtf((float)v + 1.0f);
    }
    if (i == NN - 1) offs[NN] = excl + v;
}

// CSR fill: xe[pos]=(x[r].xyz, dinv[r]) for edgeconv; rd[pos]=(r, dinv[r]) for prop
__global__ void csr_fill(const int* __restrict__ ei, const float* __restrict__ x,
                         const float* __restrict__ dinv, int* __restrict__ cursor,
                         int2* __restrict__ rd, float4* __restrict__ xe) {
    int e = blockIdx.x * 256 + threadIdx.x;
    if (e < NE) {
        int r = ei[e];
        int c = ei[NE + e];
        float dr = dinv[r];
        int pos = atomicAdd(&cursor[c], 1);
        rd[pos] = make_int2(r, __float_as_int(dr));
        xe[pos] = make_float4(x[r * 3], x[r * 3 + 1], x[r * 3 + 2], dr);
    }
}

__global__ void xw1_init(const float* __restrict__ x, const float* __restrict__ g1W,
                         const int* __restrict__ ideg, const float* __restrict__ tab,
                         float* __restrict__ xw1) {
    int gid = blockIdx.x * 256 + threadIdx.x;
    if (gid >= NN * 32) return;
    int n = gid >> 5, j = gid & 31;
    float v = (float)ideg[n] * tab[12480 + j];
    v += x[n * 3 + 0] * g1W[0 * 32 + j];
    v += x[n * 3 + 1] * g1W[1 * 32 + j];
    v += x[n * 3 + 2] * g1W[2 * 32 + j];
    xw1[gid] = v;
}

__device__ __forceinline__ float bcast_lane(float v, int t) {
    return __uint_as_float(__builtin_amdgcn_readlane(__float_as_uint(v), (unsigned)t));
}

// Edge phase only: one node per wave, halves take classes 0-4 / 5-9.
// Writes agg[n-n_start][c*32+j] as packed (fp16 hi | fp16 lo) u32.
__global__ __launch_bounds__(256, 8) void edgeconv_fused(
    const float* __restrict__ x, const int* __restrict__ offs,
    const float4* __restrict__ xe, const float* __restrict__ tab,
    unsigned int* __restrict__ agg, int n_start, int n_end) {
    int lane = threadIdx.x & 63;
    int j = lane & 31;
    int half = lane >> 5;
    int c0 = half * 5;

    float A0[5], A1[5], A2[5], B0[5], B1[5], B2[5], hb[5];
#pragma unroll
    for (int i = 0; i < 5; ++i) {
        int cb = (c0 + i) * 96;
        A0[i] = tab[cb + j];       A1[i] = tab[cb + 32 + j];       A2[i] = tab[cb + 64 + j];
        B0[i] = tab[960 + cb + j]; B1[i] = tab[960 + cb + 32 + j]; B2[i] = tab[960 + cb + 64 + j];
        hb[i] = tab[1920 + (c0 + i) * 32 + j];
    }

    int wid = blockIdx.x * 4 + (threadIdx.x >> 6);
    const int wstride = gridDim.x * 4;

    for (int n = n_start + wid; n < n_end; n += wstride) {
        float x0 = x[n * 3], x1 = x[n * 3 + 1], x2 = x[n * 3 + 2];
        float va[5], acc[5];
#pragma unroll
        for (int i = 0; i < 5; ++i) {
            va[i] = hb[i] + x0 * B0[i] + x1 * B1[i] + x2 * B2[i];
            acc[i] = 0.f;
        }
        int e0 = offs[n], e1 = offs[n + 1];
        for (int base = e0; base < e1; base += 64) {
            int ee = base + lane;
            float4 q = make_float4(0.f, 0.f, 0.f, 0.f);
            if (ee < e1) q = xe[ee];
            int cnt = e1 - base;
            if (cnt > 64) cnt = 64;
            int t = 0;
            for (; t + 1 < cnt; t += 2) {
                float px0 = bcast_lane(q.x, t),     py0 = bcast_lane(q.y, t),     pz0 = bcast_lane(q.z, t);
                float px1 = bcast_lane(q.x, t + 1), py1 = bcast_lane(q.y, t + 1), pz1 = bcast_lane(q.z, t + 1);
#pragma unroll
                for (int i = 0; i < 5; ++i)
                    acc[i] += fmaxf(va[i] + px0 * A0[i] + py0 * A1[i] + pz0 * A2[i], 0.f);
#pragma unroll
                for (int i = 0; i < 5; ++i)
                    acc[i] += fmaxf(va[i] + px1 * A0[i] + py1 * A1[i] + pz1 * A2[i], 0.f);
            }
            if (t < cnt) {
                float px = bcast_lane(q.x, t), py = bcast_lane(q.y, t), pz = bcast_lane(q.z, t);
#pragma unroll
                for (int i = 0; i < 5; ++i)
                    acc[i] += fmaxf(va[i] + px * A0[i] + py * A1[i] + pz * A2[i], 0.f);
            }
        }
        unsigned int* arow = agg + (unsigned)(n - n_start) * 320 + half * 160 + j;
#pragma unroll
        for (int i = 0; i < 5; ++i) {
            float a = acc[i];
            _Float16 hi = (_Float16)a;
            _Float16 lo = (_Float16)(a - (float)hi);
            half2v pr = {hi, lo};
            arow[i * 32] = __builtin_bit_cast(unsigned int, pr);
        }
    }
}

// Fold via MFMA: xw1[n][:] += agg[n][0:320] @ Mflat[320][32], 16 nodes/wave.
__global__ __launch_bounds__(256) void fold_mfma(
    const unsigned int* __restrict__ agg, const _Float16* __restrict__ MfragG,
    float* __restrict__ xw1, int n_start, int n_end) {
    __shared__ _Float16 Mf[20480];
    {
        const uint4* src = (const uint4*)MfragG;
        uint4* dst = (uint4*)Mf;
        for (int i = threadIdx.x; i < 2560; i += 256) dst[i] = src[i];
    }
    __syncthreads();

    int wave = blockIdx.x * 4 + (threadIdx.x >> 6);
    int lane = threadIdx.x & 63;
    int n0 = n_start + wave * 16;
    if (n0 >= n_end) return;

    int m = lane & 15, q = lane >> 4;
    int arow_n = n0 + m;
    bool rowok = arow_n < n_end;
    const unsigned int* arow = agg + (unsigned)(arow_n - n_start) * 320 + q * 8;

    const half8* mf = (const half8*)Mf;
    f32x4 acc0 = {0.f, 0.f, 0.f, 0.f};
    f32x4 acc1 = {0.f, 0.f, 0.f, 0.f};

    for (int kc = 0; kc < 10; ++kc) {
        half8 ah, al;
        if (rowok) {
            uint4 w0 = *(const uint4*)(arow + kc * 32);
            uint4 w1 = *(const uint4*)(arow + kc * 32 + 4);
            unsigned int w[8] = {w0.x, w0.y, w0.z, w0.w, w1.x, w1.y, w1.z, w1.w};
#pragma unroll
            for (int i = 0; i < 8; ++i) {
                half2v pr = __builtin_bit_cast(half2v, w[i]);
                ah[i] = pr.x;
                al[i] = pr.y;
            }
        } else {
#pragma unroll
            for (int i = 0; i < 8; ++i) { ah[i] = (_Float16)0.f; al[i] = (_Float16)0.f; }
        }
        half8 bh0 = mf[((kc * 2 + 0) * 2 + 0) * 64 + lane];
        half8 bl0 = mf[((kc * 2 + 0) * 2 + 1) * 64 + lane];
        half8 bh1 = mf[((kc * 2 + 1) * 2 + 0) * 64 + lane];
        half8 bl1 = mf[((kc * 2 + 1) * 2 + 1) * 64 + lane];
        acc0 = __builtin_amdgcn_mfma_f32_16x16x32_f16(ah, bh0, acc0, 0, 0, 0);
        acc0 = __builtin_amdgcn_mfma_f32_16x16x32_f16(al, bh0, acc0, 0, 0, 0);
        acc0 = __builtin_amdgcn_mfma_f32_16x16x32_f16(ah, bl0, acc0, 0, 0, 0);
        acc1 = __builtin_amdgcn_mfma_f32_16x16x32_f16(ah, bh1, acc1, 0, 0, 0);
        acc1 = __builtin_amdgcn_mfma_f32_16x16x32_f16(al, bh1, acc1, 0, 0, 0);
        acc1 = __builtin_amdgcn_mfma_f32_16x16x32_f16(ah, bl1, acc1, 0, 0, 0);
    }

    int jcol = lane & 15;
#pragma unroll
    for (int r = 0; r < 4; ++r) {
        int node = n0 + q * 4 + r;
        if (node < n_end) {
            xw1[node * 32 + jcol] += acc0[r];
            xw1[node * 32 + 16 + jcol] += acc1[r];
        }
    }
}

// One node per wave64; half-waves take even/odd CSR slots; (r,dinv_r) one b64 load.
__global__ __launch_bounds__(256, 4) void prop_wave(
    const int* __restrict__ offs, const int2* __restrict__ rd,
    const float* __restrict__ xw, const float* __restrict__ dinv,
    float* __restrict__ out) {
    int n = blockIdx.x * 4 + (threadIdx.x >> 6);
    if (n >= NN) return;
    int lane = threadIdx.x & 63;
    int j = lane & 31;
    int half = lane >> 5;
    int e0 = offs[n], e1 = offs[n + 1];
    float s0 = 0.f, s1 = 0.f;
    int e = e0 + half;
    for (; e + 2 < e1; e += 4) {
        int2 p0 = rd[e];
        int2 p1 = rd[e + 2];
        s0 += xw[p0.x * 32 + j] * __int_as_float(p0.y);
        s1 += xw[p1.x * 32 + j] * __int_as_float(p1.y);
    }
    if (e < e1) {
        int2 p = rd[e];
        s0 += xw[p.x * 32 + j] * __int_as_float(p.y);
    }
    float s = s0 + s1;
    s += __shfl_xor(s, 32, 64);
    if (lane < 32) {
        float di = dinv[n];
        out[n * 32 + j] = di * s + di * di * xw[n * 32 + j];
    }
}

__global__ void xw2_kernel(const float* __restrict__ h1raw, const float* __restrict__ g1b,
                           const float* __restrict__ g2W, float* __restrict__ xw2) {
    int gid = blockIdx.x * 256 + threadIdx.x;
    if (gid >= NN * 32) return;
    int n = gid >> 5, j = gid & 31;
    float s = 0.f;
    for (int k = 0; k < 32; ++k) {
        float h = fmaxf(h1raw[n * 32 + k] + g1b[k], 0.0f);
        s += h * g2W[k * 32 + j];
    }
    xw2[gid] = s;
}

__global__ void pool_seg(const float* __restrict__ h2, const float* __restrict__ g2b,
                         const int* __restrict__ batch, float* __restrict__ pooled,
                         float* __restrict__ counts) {
    int grp = threadIdx.x >> 5, j = threadIdx.x & 31;
    int base = (blockIdx.x * 8 + grp) * 64;
    if (base >= NN) return;
    float bj = g2b[j];
    float acc = 0.f, cnt = 0.f;
    int curg = -1;
    int lim = base + 64;
    if (lim > NN) lim = NN;
    for (int n = base; n < lim; ++n) {
        int g = batch[n];
        if (g != curg) {
            if (curg >= 0) {
                atomicAdd(&pooled[curg * 32 + j], acc);
                if (j == 0) atomicAdd(&counts[curg], cnt);
            }
            curg = g; acc = 0.f; cnt = 0.f;
        }
        acc += fmaxf(h2[n * 32 + j] + bj, 0.f);
        cnt += 1.f;
    }
    if (curg >= 0) {
        atomicAdd(&pooled[curg * 32 + j], acc);
        if (j == 0) atomicAdd(&counts[curg], cnt);
    }
}

__global__ void final_kernel(const float* __restrict__ pooled, const float* __restrict__ counts,
                             const float* __restrict__ clsW, const float* __restrict__ clsb,
                             float* __restrict__ out) {
    int tid = threadIdx.x;
    if (tid >= GG * CC) return;
    int g = tid / CC, cc = tid % CC;
    float inv = 1.0f / fmaxf(counts[g], 1.0f);
    float s = clsb[cc];
    for (int j = 0; j < 32; ++j) s += (pooled[g * 32 + j] * inv) * clsW[j * CC + cc];
    out[g * CC + cc] = s;
}

extern "C" void kernel_launch(void* const* d_in, const int* in_sizes, int n_in,
                              void* d_out, int out_size, void* d_ws, size_t ws_size,
                              hipStream_t stream) {
    const float* x     = (const float*)d_in[0];
    const int*   ei    = (const int*)d_in[1];
    const int*   batch = (const int*)d_in[2];
    const float* fW    = (const float*)d_in[3];
    const float* fb    = (const float*)d_in[4];
    const float* W1    = (const float*)d_in[5];
    const float* b1    = (const float*)d_in[6];
    const float* W2    = (const float*)d_in[7];
    const float* b2    = (const float*)d_in[8];
    const float* g1W   = (const float*)d_in[9];
    const float* g1b   = (const float*)d_in[10];
    const float* g2W   = (const float*)d_in[11];
    const float* g2b   = (const float*)d_in[12];
    const float* clsW  = (const float*)d_in[13];
    const float* clsb  = (const float*)d_in[14];
    float* out = (float*)d_out;

    float4*       xe     = (float4*)d_ws;
    unsigned int* agg    = (unsigned int*)(xe + NE);           // STRIP*320 u32 = 32 MB
    int2*         rd     = (int2*)(agg + (size_t)STRIP * 320);
    int*          ideg   = (int*)(rd + NE);
    int*          offs   = ideg + NN;
    int*          cursor = offs + NN + 1;
    int*          bsum   = cursor + NN;
    float*        dinv   = (float*)(bsum + 512);
    float*        tab    = dinv + NN;
    _Float16*     Mfrag  = (_Float16*)(tab + 16384);           // 20480 halfs
    float*        xw1    = tab + 16384 + 10240;
    float*        U      = xw1 + NN * 32;
    float*        V      = U + NN * 32;
    float*        pooled = V + NN * 32;
    float*        counts = pooled + GG * 32;

    const int nodeBlocks = (NN * 32 + 255) / 256;
    const int edgeBlocks = (NE + 255) / 256;
    const int waveBlocks = (NN + 3) / 4;

    zero_int<<<(NN + 255) / 256, 256, 0, stream>>>(ideg, NN);
    zero_f<<<(GG * 33 + 255) / 256, 256, 0, stream>>>(pooled, GG * 33);
    precompute_small<<<10, 1024, 0, stream>>>(fW, fb, W1, b1, W2, b2, g1W, tab);
    mfrag_kernel<<<10, 256, 0, stream>>>(tab, Mfrag);

    deg_int<<<edgeBlocks, 256, 0, stream>>>(ei, ideg);
    scan_phase1<<<SBLK, 256, 0, stream>>>(ideg, bsum);
    scan_phase2<<<1, 512, 0, stream>>>(bsum);
    scan_phase3<<<SBLK, 256, 0, stream>>>(ideg, bsum, offs, cursor, dinv);
    csr_fill<<<edgeBlocks, 256, 0, stream>>>(ei, x, dinv, cursor, rd, xe);

    xw1_init<<<nodeBlocks, 256, 0, stream>>>(x, g1W, ideg, tab, xw1);

    for (int s = 0; s < NN / STRIP; ++s) {
        int ns = s * STRIP, ne2 = ns + STRIP;
        edgeconv_fused<<<640, 256, 0, stream>>>(x, offs, xe, tab, agg, ns, ne2);
        int foldWaves = (STRIP + 15) / 16;
        fold_mfma<<<(foldWaves + 3) / 4, 256, 0, stream>>>(agg, Mfrag, xw1, ns, ne2);
    }

    prop_wave<<<waveBlocks, 256, 0, stream>>>(offs, rd, xw1, dinv, U);   // h1raw
    xw2_kernel<<<nodeBlocks, 256, 0, stream>>>(U, g1b, g2W, V);          // xw2
    prop_wave<<<waveBlocks, 256, 0, stream>>>(offs, rd, V, dinv, xw1);   // h2raw
    pool_seg<<<(NN + 511) / 512, 256, 0, stream>>>(xw1, g2b, batch, pooled, counts);
    final_kernel<<<1, 640, 0, stream>>>(pooled, counts, clsW, clsb, out);
}

// Round 7
// 662.723 us; speedup vs baseline: 5.2267x; 1.0301x over previous
//
#include <hip/hip_runtime.h>

#define NN 100000
#define NE 1600000
#define HH 32
#define CC 10
#define GG 64
#define STRIP 25000
#define SBLK ((NN + 255) / 256)   // 391 scan blocks

typedef _Float16 half8 __attribute__((ext_vector_type(8)));
typedef _Float16 half2v __attribute__((ext_vector_type(2)));
typedef float f32x4 __attribute__((ext_vector_type(4)));

// ---------------- workspace layout ----------------
// float4 xpad[NN]; uint agg[STRIP*320]; int2 rd[NE]; int ideg[NN], offs[NN+1], cursor[NN];
// int bsum[512]; float dinv[NN], tab[16384]; _Float16 Mfrag[20480];
// float xw1[NN*32], U, V, pooled, counts

__global__ void zero_int(int* p, int n) {
    int i = blockIdx.x * 256 + threadIdx.x;
    if (i < n) p[i] = 0;
}

__global__ void zero_f(float* p, int n) {
    int i = blockIdx.x * 256 + threadIdx.x;
    if (i < n) p[i] = 0.0f;
}

__global__ void precompute_small(const float* __restrict__ fW, const float* __restrict__ fb,
                                 const float* __restrict__ W1, const float* __restrict__ b1,
                                 const float* __restrict__ W2, const float* __restrict__ b2,
                                 const float* __restrict__ g1W, float* __restrict__ tab) {
    int c = blockIdx.x;
    int k = threadIdx.x >> 5;
    int j = threadIdx.x & 31;
    float m = 0.f;
    for (int mm = 0; mm < 32; ++mm)
        m += W2[k * 32 + mm] * g1W[(3 + 32 * c + mm) * 32 + j];
    tab[2240 + c * 1024 + k * 32 + j] = m;

    if (k < 3) {
        float a = 0.f, b = 0.f;
        for (int i = 0; i < 32; ++i) {
            float w = fW[c * 96 + k * 32 + i];
            a += w * W1[i * 32 + j];
            b += w * W1[(32 + i) * 32 + j];
        }
        tab[c * 96 + k * 32 + j] = a;
        tab[960 + c * 96 + k * 32 + j] = b;
    } else if (k == 3) {
        float h = b1[j];
        for (int i = 0; i < 32; ++i)
            h += fb[c * 32 + i] * (W1[i * 32 + j] + W1[(32 + i) * 32 + j]);
        tab[1920 + c * 32 + j] = h;
    } else if (k == 4 && c == 0) {
        float t = 0.f;
        for (int cc2 = 0; cc2 < CC; ++cc2)
            for (int mm = 0; mm < 32; ++mm)
                t += b2[mm] * g1W[(3 + 32 * cc2 + mm) * 32 + j];
        tab[12480 + j] = t;
    }
}

// Pre-swizzle Mflat[320][32] into MFMA B-fragment order, fp16 hi/lo planes.
__global__ void mfrag_kernel(const float* __restrict__ tab, _Float16* __restrict__ Mfrag) {
    int gid = blockIdx.x * 256 + threadIdx.x;   // [0, 2560)
    if (gid >= 2560) return;
    int set = gid >> 6, l = gid & 63;
    int p = set & 1, jt = (set >> 1) & 1, kc = set >> 2;
    int j = jt * 16 + (l & 15);
    int kbase = kc * 32 + (l >> 4) * 8;
#pragma unroll
    for (int i = 0; i < 8; ++i) {
        float v = tab[2240 + (kbase + i) * 32 + j];
        _Float16 hi = (_Float16)v;
        Mfrag[gid * 8 + i] = p ? (_Float16)(v - (float)hi) : hi;
    }
}

__global__ void deg_int(const int* __restrict__ ei, int* __restrict__ ideg) {
    int e = blockIdx.x * 256 + threadIdx.x;
    if (e < NE) atomicAdd(&ideg[ei[NE + e]], 1);
}

// -------- hierarchical scan --------
__global__ void scan_phase1(const int* __restrict__ ideg, int* __restrict__ bsum) {
    __shared__ int sh[256];
    int b = blockIdx.x, t = threadIdx.x;
    int i = b * 256 + t;
    sh[t] = (i < NN) ? ideg[i] : 0;
    __syncthreads();
    for (int off = 128; off > 0; off >>= 1) {
        if (t < off) sh[t] += sh[t + off];
        __syncthreads();
    }
    if (t == 0) bsum[b] = sh[0];
}

__global__ void scan_phase2(int* __restrict__ bsum) {
    __shared__ int sh[512];
    int t = threadIdx.x;
    int v = (t < SBLK) ? bsum[t] : 0;
    sh[t] = v;
    __syncthreads();
    for (int off = 1; off < 512; off <<= 1) {
        int add = (t >= off) ? sh[t - off] : 0;
        __syncthreads();
        sh[t] += add;
        __syncthreads();
    }
    if (t < SBLK) bsum[t] = sh[t] - v;   // exclusive
}

// phase3: per-block scan + offset; fills offs/cursor/dinv/xpad
__global__ void scan_phase3(const int* __restrict__ ideg, const int* __restrict__ bsum,
                            const float* __restrict__ x, int* __restrict__ offs,
                            int* __restrict__ cursor, float* __restrict__ dinv,
                            float4* __restrict__ xpad) {
    __shared__ int sh[256];
    int b = blockIdx.x, t = threadIdx.x;
    int i = b * 256 + t;
    int v = (i < NN) ? ideg[i] : 0;
    sh[t] = v;
    __syncthreads();
    for (int off = 1; off < 256; off <<= 1) {
        int add = (t >= off) ? sh[t - off] : 0;
        __syncthreads();
        sh[t] += add;
        __syncthreads();
    }
    int excl = sh[t] - v + bsum[b];
    if (i < NN) {
        offs[i] = excl;
        cursor[i] = excl;
        float di = rsqrtf((float)v + 1.0f);
        dinv[i] = di;
        xpad[i] = make_float4(x[i * 3], x[i * 3 + 1], x[i * 3 + 2], di);
    }
    if (i == NN - 1) offs[NN] = excl + v;
}

// CSR fill: rd[pos]=(r, dinv[r]) only — 8 B/edge scatter
__global__ void csr_fill(const int* __restrict__ ei, const float* __restrict__ dinv,
                         int* __restrict__ cursor, int2* __restrict__ rd) {
    int e = blockIdx.x * 256 + threadIdx.x;
    if (e < NE) {
        int r = ei[e];
        int c = ei[NE + e];
        float dr = dinv[r];
        int pos = atomicAdd(&cursor[c], 1);
        rd[pos] = make_int2(r, __float_as_int(dr));
    }
}

__global__ void xw1_init(const float* __restrict__ x, const float* __restrict__ g1W,
                         const int* __restrict__ ideg, const float* __restrict__ tab,
                         float* __restrict__ xw1) {
    int gid = blockIdx.x * 256 + threadIdx.x;
    if (gid >= NN * 32) return;
    int n = gid >> 5, j = gid & 31;
    float v = (float)ideg[n] * tab[12480 + j];
    v += x[n * 3 + 0] * g1W[0 * 32 + j];
    v += x[n * 3 + 1] * g1W[1 * 32 + j];
    v += x[n * 3 + 2] * g1W[2 * 32 + j];
    xw1[gid] = v;
}

__device__ __forceinline__ float bcast_lane(float v, int t) {
    return __uint_as_float(__builtin_amdgcn_readlane(__float_as_uint(v), (unsigned)t));
}

// Edge phase: one node per wave, halves take classes 0-4 / 5-9.
// Lane-parallel rd load (coalesced), gather xpad[r] (L2-resident 1.6 MB),
// broadcast via v_readlane. Writes agg packed (fp16 hi | fp16 lo).
__global__ __launch_bounds__(256, 8) void edgeconv_fused(
    const float4* __restrict__ xpad, const int* __restrict__ offs,
    const int2* __restrict__ rd, const float* __restrict__ tab,
    unsigned int* __restrict__ agg, int n_start, int n_end) {
    int lane = threadIdx.x & 63;
    int j = lane & 31;
    int half = lane >> 5;
    int c0 = half * 5;

    float A0[5], A1[5], A2[5], B0[5], B1[5], B2[5], hb[5];
#pragma unroll
    for (int i = 0; i < 5; ++i) {
        int cb = (c0 + i) * 96;
        A0[i] = tab[cb + j];       A1[i] = tab[cb + 32 + j];       A2[i] = tab[cb + 64 + j];
        B0[i] = tab[960 + cb + j]; B1[i] = tab[960 + cb + 32 + j]; B2[i] = tab[960 + cb + 64 + j];
        hb[i] = tab[1920 + (c0 + i) * 32 + j];
    }

    int wid = blockIdx.x * 4 + (threadIdx.x >> 6);
    const int wstride = gridDim.x * 4;

    for (int n = n_start + wid; n < n_end; n += wstride) {
        float4 xn = xpad[n];
        float va[5], acc[5];
#pragma unroll
        for (int i = 0; i < 5; ++i) {
            va[i] = hb[i] + xn.x * B0[i] + xn.y * B1[i] + xn.z * B2[i];
            acc[i] = 0.f;
        }
        int e0 = offs[n], e1 = offs[n + 1];
        for (int base = e0; base < e1; base += 64) {
            int ee = base + lane;
            int r = (ee < e1) ? rd[ee].x : 0;
            float4 q = xpad[r];
            int cnt = e1 - base;
            if (cnt > 64) cnt = 64;
            int t = 0;
            for (; t + 1 < cnt; t += 2) {
                float px0 = bcast_lane(q.x, t),     py0 = bcast_lane(q.y, t),     pz0 = bcast_lane(q.z, t);
                float px1 = bcast_lane(q.x, t + 1), py1 = bcast_lane(q.y, t + 1), pz1 = bcast_lane(q.z, t + 1);
#pragma unroll
                for (int i = 0; i < 5; ++i)
                    acc[i] += fmaxf(va[i] + px0 * A0[i] + py0 * A1[i] + pz0 * A2[i], 0.f);
#pragma unroll
                for (int i = 0; i < 5; ++i)
                    acc[i] += fmaxf(va[i] + px1 * A0[i] + py1 * A1[i] + pz1 * A2[i], 0.f);
            }
            if (t < cnt) {
                float px = bcast_lane(q.x, t), py = bcast_lane(q.y, t), pz = bcast_lane(q.z, t);
#pragma unroll
                for (int i = 0; i < 5; ++i)
                    acc[i] += fmaxf(va[i] + px * A0[i] + py * A1[i] + pz * A2[i], 0.f);
            }
        }
        unsigned int* arow = agg + (unsigned)(n - n_start) * 320 + half * 160 + j;
#pragma unroll
        for (int i = 0; i < 5; ++i) {
            float a = acc[i];
            _Float16 hi = (_Float16)a;
            _Float16 lo = (_Float16)(a - (float)hi);
            half2v pr = {hi, lo};
            arow[i * 32] = __builtin_bit_cast(unsigned int, pr);
        }
    }
}

// Fold via MFMA: xw1[n][:] += agg[n][0:320] @ Mflat[320][32], 16 nodes/wave.
__global__ __launch_bounds__(256) void fold_mfma(
    const unsigned int* __restrict__ agg, const _Float16* __restrict__ MfragG,
    float* __restrict__ xw1, int n_start, int n_end) {
    __shared__ _Float16 Mf[20480];
    {
        const uint4* src = (const uint4*)MfragG;
        uint4* dst = (uint4*)Mf;
        for (int i = threadIdx.x; i < 2560; i += 256) dst[i] = src[i];
    }
    __syncthreads();

    int wave = blockIdx.x * 4 + (threadIdx.x >> 6);
    int lane = threadIdx.x & 63;
    int n0 = n_start + wave * 16;
    if (n0 >= n_end) return;

    int m = lane & 15, q = lane >> 4;
    int arow_n = n0 + m;
    bool rowok = arow_n < n_end;
    const unsigned int* arow = agg + (unsigned)(arow_n - n_start) * 320 + q * 8;

    const half8* mf = (const half8*)Mf;
    f32x4 acc0 = {0.f, 0.f, 0.f, 0.f};
    f32x4 acc1 = {0.f, 0.f, 0.f, 0.f};

    for (int kc = 0; kc < 10; ++kc) {
        half8 ah, al;
        if (rowok) {
            uint4 w0 = *(const uint4*)(arow + kc * 32);
            uint4 w1 = *(const uint4*)(arow + kc * 32 + 4);
            unsigned int w[8] = {w0.x, w0.y, w0.z, w0.w, w1.x, w1.y, w1.z, w1.w};
#pragma unroll
            for (int i = 0; i < 8; ++i) {
                half2v pr = __builtin_bit_cast(half2v, w[i]);
                ah[i] = pr.x;
                al[i] = pr.y;
            }
        } else {
#pragma unroll
            for (int i = 0; i < 8; ++i) { ah[i] = (_Float16)0.f; al[i] = (_Float16)0.f; }
        }
        half8 bh0 = mf[((kc * 2 + 0) * 2 + 0) * 64 + lane];
        half8 bl0 = mf[((kc * 2 + 0) * 2 + 1) * 64 + lane];
        half8 bh1 = mf[((kc * 2 + 1) * 2 + 0) * 64 + lane];
        half8 bl1 = mf[((kc * 2 + 1) * 2 + 1) * 64 + lane];
        acc0 = __builtin_amdgcn_mfma_f32_16x16x32_f16(ah, bh0, acc0, 0, 0, 0);
        acc0 = __builtin_amdgcn_mfma_f32_16x16x32_f16(al, bh0, acc0, 0, 0, 0);
        acc0 = __builtin_amdgcn_mfma_f32_16x16x32_f16(ah, bl0, acc0, 0, 0, 0);
        acc1 = __builtin_amdgcn_mfma_f32_16x16x32_f16(ah, bh1, acc1, 0, 0, 0);
        acc1 = __builtin_amdgcn_mfma_f32_16x16x32_f16(al, bh1, acc1, 0, 0, 0);
        acc1 = __builtin_amdgcn_mfma_f32_16x16x32_f16(ah, bl1, acc1, 0, 0, 0);
    }

    int jcol = lane & 15;
#pragma unroll
    for (int r = 0; r < 4; ++r) {
        int node = n0 + q * 4 + r;
        if (node < n_end) {
            xw1[node * 32 + jcol] += acc0[r];
            xw1[node * 32 + 16 + jcol] += acc1[r];
        }
    }
}

// One node per wave64; half-waves take even/odd CSR slots; (r,dinv_r) one b64 load.
__global__ __launch_bounds__(256, 4) void prop_wave(
    const int* __restrict__ offs, const int2* __restrict__ rd,
    const float* __restrict__ xw, const float* __restrict__ dinv,
    float* __restrict__ out) {
    int n = blockIdx.x * 4 + (threadIdx.x >> 6);
    if (n >= NN) return;
    int lane = threadIdx.x & 63;
    int j = lane & 31;
    int half = lane >> 5;
    int e0 = offs[n], e1 = offs[n + 1];
    float s0 = 0.f, s1 = 0.f;
    int e = e0 + half;
    for (; e + 2 < e1; e += 4) {
        int2 p0 = rd[e];
        int2 p1 = rd[e + 2];
        s0 += xw[p0.x * 32 + j] * __int_as_float(p0.y);
        s1 += xw[p1.x * 32 + j] * __int_as_float(p1.y);
    }
    if (e < e1) {
        int2 p = rd[e];
        s0 += xw[p.x * 32 + j] * __int_as_float(p.y);
    }
    float s = s0 + s1;
    s += __shfl_xor(s, 32, 64);
    if (lane < 32) {
        float di = dinv[n];
        out[n * 32 + j] = di * s + di * di * xw[n * 32 + j];
    }
}

__global__ void xw2_kernel(const float* __restrict__ h1raw, const float* __restrict__ g1b,
                           const float* __restrict__ g2W, float* __restrict__ xw2) {
    int gid = blockIdx.x * 256 + threadIdx.x;
    if (gid >= NN * 32) return;
    int n = gid >> 5, j = gid & 31;
    float s = 0.f;
    for (int k = 0; k < 32; ++k) {
        float h = fmaxf(h1raw[n * 32 + k] + g1b[k], 0.0f);
        s += h * g2W[k * 32 + j];
    }
    xw2[gid] = s;
}

__global__ void pool_seg(const float* __restrict__ h2, const float* __restrict__ g2b,
                         const int* __restrict__ batch, float* __restrict__ pooled,
                         float* __restrict__ counts) {
    int grp = threadIdx.x >> 5, j = threadIdx.x & 31;
    int base = (blockIdx.x * 8 + grp) * 64;
    if (base >= NN) return;
    float bj = g2b[j];
    float acc = 0.f, cnt = 0.f;
    int curg = -1;
    int lim = base + 64;
    if (lim > NN) lim = NN;
    for (int n = base; n < lim; ++n) {
        int g = batch[n];
        if (g != curg) {
            if (curg >= 0) {
                atomicAdd(&pooled[curg * 32 + j], acc);
                if (j == 0) atomicAdd(&counts[curg], cnt);
            }
            curg = g; acc = 0.f; cnt = 0.f;
        }
        acc += fmaxf(h2[n * 32 + j] + bj, 0.f);
        cnt += 1.f;
    }
    if (curg >= 0) {
        atomicAdd(&pooled[curg * 32 + j], acc);
        if (j == 0) atomicAdd(&counts[curg], cnt);
    }
}

__global__ void final_kernel(const float* __restrict__ pooled, const float* __restrict__ counts,
                             const float* __restrict__ clsW, const float* __restrict__ clsb,
                             float* __restrict__ out) {
    int tid = threadIdx.x;
    if (tid >= GG * CC) return;
    int g = tid / CC, cc = tid % CC;
    float inv = 1.0f / fmaxf(counts[g], 1.0f);
    float s = clsb[cc];
    for (int j = 0; j < 32; ++j) s += (pooled[g * 32 + j] * inv) * clsW[j * CC + cc];
    out[g * CC + cc] = s;
}

extern "C" void kernel_launch(void* const* d_in, const int* in_sizes, int n_in,
                              void* d_out, int out_size, void* d_ws, size_t ws_size,
                              hipStream_t stream) {
    const float* x     = (const float*)d_in[0];
    const int*   ei    = (const int*)d_in[1];
    const int*   batch = (const int*)d_in[2];
    const float* fW    = (const float*)d_in[3];
    const float* fb    = (const float*)d_in[4];
    const float* W1    = (const float*)d_in[5];
    const float* b1    = (const float*)d_in[6];
    const float* W2    = (const float*)d_in[7];
    const float* b2    = (const float*)d_in[8];
    const float* g1W   = (const float*)d_in[9];
    const float* g1b   = (const float*)d_in[10];
    const float* g2W   = (const float*)d_in[11];
    const float* g2b   = (const float*)d_in[12];
    const float* clsW  = (const float*)d_in[13];
    const float* clsb  = (const float*)d_in[14];
    float* out = (float*)d_out;

    float4*       xpad   = (float4*)d_ws;                      // NN float4 = 1.6 MB
    unsigned int* agg    = (unsigned int*)(xpad + NN);         // STRIP*320 u32 = 32 MB
    int2*         rd     = (int2*)(agg + (size_t)STRIP * 320);
    int*          ideg   = (int*)(rd + NE);
    int*          offs   = ideg + NN;
    int*          cursor = offs + NN + 1;
    int*          bsum   = cursor + NN;
    float*        dinv   = (float*)(bsum + 512);
    float*        tab    = dinv + NN;
    _Float16*     Mfrag  = (_Float16*)(tab + 16384);           // 20480 halfs
    float*        xw1    = tab + 16384 + 10240;
    float*        U      = xw1 + NN * 32;
    float*        V      = U + NN * 32;
    float*        pooled = V + NN * 32;
    float*        counts = pooled + GG * 32;

    const int nodeBlocks = (NN * 32 + 255) / 256;
    const int edgeBlocks = (NE + 255) / 256;
    const int waveBlocks = (NN + 3) / 4;

    zero_int<<<(NN + 255) / 256, 256, 0, stream>>>(ideg, NN);
    zero_f<<<(GG * 33 + 255) / 256, 256, 0, stream>>>(pooled, GG * 33);
    precompute_small<<<10, 1024, 0, stream>>>(fW, fb, W1, b1, W2, b2, g1W, tab);
    mfrag_kernel<<<10, 256, 0, stream>>>(tab, Mfrag);

    deg_int<<<edgeBlocks, 256, 0, stream>>>(ei, ideg);
    scan_phase1<<<SBLK, 256, 0, stream>>>(ideg, bsum);
    scan_phase2<<<1, 512, 0, stream>>>(bsum);
    scan_phase3<<<SBLK, 256, 0, stream>>>(ideg, bsum, x, offs, cursor, dinv, xpad);
    csr_fill<<<edgeBlocks, 256, 0, stream>>>(ei, dinv, cursor, rd);

    xw1_init<<<nodeBlocks, 256, 0, stream>>>(x, g1W, ideg, tab, xw1);

    for (int s = 0; s < NN / STRIP; ++s) {
        int ns = s * STRIP, ne2 = ns + STRIP;
        edgeconv_fused<<<2048, 256, 0, stream>>>(xpad, offs, rd, tab, agg, ns, ne2);
        int foldWaves = (STRIP + 15) / 16;
        fold_mfma<<<(foldWaves + 3) / 4, 256, 0, stream>>>(agg, Mfrag, xw1, ns, ne2);
    }

    prop_wave<<<waveBlocks, 256, 0, stream>>>(offs, rd, xw1, dinv, U);   // h1raw
    xw2_kernel<<<nodeBlocks, 256, 0, stream>>>(U, g1b, g2W, V);          // xw2
    prop_wave<<<waveBlocks, 256, 0, stream>>>(offs, rd, V, dinv, xw1);   // h2raw
    pool_seg<<<(NN + 511) / 512, 256, 0, stream>>>(xw1, g2b, batch, pooled, counts);
    final_kernel<<<1, 640, 0, stream>>>(pooled, counts, clsW, clsb, out);
}

// Round 8
// 578.910 us; speedup vs baseline: 5.9834x; 1.1448x over previous
//
#include <hip/hip_runtime.h>

#define NN 100000
#define NE 1600000
#define HH 32
#define CC 10
#define GG 64
#define STRIP 25000
#define SBLK ((NN + 255) / 256)   // 391 scan blocks

typedef _Float16 half8 __attribute__((ext_vector_type(8)));
typedef _Float16 half2v __attribute__((ext_vector_type(2)));
typedef float f32x4 __attribute__((ext_vector_type(4)));

// ---------------- workspace layout ----------------
// float4 xpad[NN]; uint agg[STRIP*320]; int csr_row[NE], rank[NE], ideg[NN], offs[NN+1];
// int bsum[512]; float dinv[NN], tab[16384]; _Float16 Mfrag[20480];
// float xw1[NN*32], U, V, pooled, counts

__global__ void zero_int(int* p, int n) {
    int i = blockIdx.x * 256 + threadIdx.x;
    if (i < n) p[i] = 0;
}

__global__ void zero_f(float* p, int n) {
    int i = blockIdx.x * 256 + threadIdx.x;
    if (i < n) p[i] = 0.0f;
}

__global__ void precompute_small(const float* __restrict__ fW, const float* __restrict__ fb,
                                 const float* __restrict__ W1, const float* __restrict__ b1,
                                 const float* __restrict__ W2, const float* __restrict__ b2,
                                 const float* __restrict__ g1W, float* __restrict__ tab) {
    int c = blockIdx.x;
    int k = threadIdx.x >> 5;
    int j = threadIdx.x & 31;
    float m = 0.f;
    for (int mm = 0; mm < 32; ++mm)
        m += W2[k * 32 + mm] * g1W[(3 + 32 * c + mm) * 32 + j];
    tab[2240 + c * 1024 + k * 32 + j] = m;

    if (k < 3) {
        float a = 0.f, b = 0.f;
        for (int i = 0; i < 32; ++i) {
            float w = fW[c * 96 + k * 32 + i];
            a += w * W1[i * 32 + j];
            b += w * W1[(32 + i) * 32 + j];
        }
        tab[c * 96 + k * 32 + j] = a;
        tab[960 + c * 96 + k * 32 + j] = b;
    } else if (k == 3) {
        float h = b1[j];
        for (int i = 0; i < 32; ++i)
            h += fb[c * 32 + i] * (W1[i * 32 + j] + W1[(32 + i) * 32 + j]);
        tab[1920 + c * 32 + j] = h;
    } else if (k == 4 && c == 0) {
        float t = 0.f;
        for (int cc2 = 0; cc2 < CC; ++cc2)
            for (int mm = 0; mm < 32; ++mm)
                t += b2[mm] * g1W[(3 + 32 * cc2 + mm) * 32 + j];
        tab[12480 + j] = t;
    }
}

// Pre-swizzle Mflat[320][32] into MFMA B-fragment order, fp16 hi/lo planes.
__global__ void mfrag_kernel(const float* __restrict__ tab, _Float16* __restrict__ Mfrag) {
    int gid = blockIdx.x * 256 + threadIdx.x;   // [0, 2560)
    if (gid >= 2560) return;
    int set = gid >> 6, l = gid & 63;
    int p = set & 1, jt = (set >> 1) & 1, kc = set >> 2;
    int j = jt * 16 + (l & 15);
    int kbase = kc * 32 + (l >> 4) * 8;
#pragma unroll
    for (int i = 0; i < 8; ++i) {
        float v = tab[2240 + (kbase + i) * 32 + j];
        _Float16 hi = (_Float16)v;
        Mfrag[gid * 8 + i] = p ? (_Float16)(v - (float)hi) : hi;
    }
}

// degree count + per-edge rank (rank = arrival order within destination)
__global__ void deg_rank(const int* __restrict__ ei, int* __restrict__ ideg,
                         int* __restrict__ rank) {
    int e = blockIdx.x * 256 + threadIdx.x;
    if (e < NE) rank[e] = atomicAdd(&ideg[ei[NE + e]], 1);
}

// -------- hierarchical scan --------
__global__ void scan_phase1(const int* __restrict__ ideg, int* __restrict__ bsum) {
    __shared__ int sh[256];
    int b = blockIdx.x, t = threadIdx.x;
    int i = b * 256 + t;
    sh[t] = (i < NN) ? ideg[i] : 0;
    __syncthreads();
    for (int off = 128; off > 0; off >>= 1) {
        if (t < off) sh[t] += sh[t + off];
        __syncthreads();
    }
    if (t == 0) bsum[b] = sh[0];
}

__global__ void scan_phase2(int* __restrict__ bsum) {
    __shared__ int sh[512];
    int t = threadIdx.x;
    int v = (t < SBLK) ? bsum[t] : 0;
    sh[t] = v;
    __syncthreads();
    for (int off = 1; off < 512; off <<= 1) {
        int add = (t >= off) ? sh[t - off] : 0;
        __syncthreads();
        sh[t] += add;
        __syncthreads();
    }
    if (t < SBLK) bsum[t] = sh[t] - v;   // exclusive
}

// phase3: per-block scan + offset; fills offs/dinv/xpad
__global__ void scan_phase3(const int* __restrict__ ideg, const int* __restrict__ bsum,
                            const float* __restrict__ x, int* __restrict__ offs,
                            float* __restrict__ dinv, float4* __restrict__ xpad) {
    __shared__ int sh[256];
    int b = blockIdx.x, t = threadIdx.x;
    int i = b * 256 + t;
    int v = (i < NN) ? ideg[i] : 0;
    sh[t] = v;
    __syncthreads();
    for (int off = 1; off < 256; off <<= 1) {
        int add = (t >= off) ? sh[t - off] : 0;
        __syncthreads();
        sh[t] += add;
        __syncthreads();
    }
    int excl = sh[t] - v + bsum[b];
    if (i < NN) {
        offs[i] = excl;
        float di = rsqrtf((float)v + 1.0f);
        dinv[i] = di;
        xpad[i] = make_float4(x[i * 3], x[i * 3 + 1], x[i * 3 + 2], di);
    }
    if (i == NN - 1) offs[NN] = excl + v;
}

// CSR place: no atomics — pos = offs[col] + rank[e]; 4 B scatter
__global__ void csr_place(const int* __restrict__ ei, const int* __restrict__ rank,
                          const int* __restrict__ offs, int* __restrict__ csr_row) {
    int e = blockIdx.x * 256 + threadIdx.x;
    if (e < NE) {
        int r = ei[e];
        int c = ei[NE + e];
        csr_row[offs[c] + rank[e]] = r;
    }
}

__global__ void xw1_init(const float* __restrict__ x, const float* __restrict__ g1W,
                         const int* __restrict__ ideg, const float* __restrict__ tab,
                         float* __restrict__ xw1) {
    int gid = blockIdx.x * 256 + threadIdx.x;
    if (gid >= NN * 32) return;
    int n = gid >> 5, j = gid & 31;
    float v = (float)ideg[n] * tab[12480 + j];
    v += x[n * 3 + 0] * g1W[0 * 32 + j];
    v += x[n * 3 + 1] * g1W[1 * 32 + j];
    v += x[n * 3 + 2] * g1W[2 * 32 + j];
    xw1[gid] = v;
}

__device__ __forceinline__ float bcast_lane(float v, int t) {
    return __uint_as_float(__builtin_amdgcn_readlane(__float_as_uint(v), (unsigned)t));
}

// Edge phase: one node per wave, halves take classes 0-4 / 5-9.
// Lane-parallel csr_row load (coalesced), gather xpad[r] (L2-resident),
// broadcast via v_readlane. Writes agg packed (fp16 hi | fp16 lo).
__global__ __launch_bounds__(256, 8) void edgeconv_fused(
    const float4* __restrict__ xpad, const int* __restrict__ offs,
    const int* __restrict__ csr_row, const float* __restrict__ tab,
    unsigned int* __restrict__ agg, int n_start, int n_end) {
    int lane = threadIdx.x & 63;
    int j = lane & 31;
    int half = lane >> 5;
    int c0 = half * 5;

    float A0[5], A1[5], A2[5], B0[5], B1[5], B2[5], hb[5];
#pragma unroll
    for (int i = 0; i < 5; ++i) {
        int cb = (c0 + i) * 96;
        A0[i] = tab[cb + j];       A1[i] = tab[cb + 32 + j];       A2[i] = tab[cb + 64 + j];
        B0[i] = tab[960 + cb + j]; B1[i] = tab[960 + cb + 32 + j]; B2[i] = tab[960 + cb + 64 + j];
        hb[i] = tab[1920 + (c0 + i) * 32 + j];
    }

    int wid = blockIdx.x * 4 + (threadIdx.x >> 6);
    const int wstride = gridDim.x * 4;

    for (int n = n_start + wid; n < n_end; n += wstride) {
        float4 xn = xpad[n];
        float va[5], acc[5];
#pragma unroll
        for (int i = 0; i < 5; ++i) {
            va[i] = hb[i] + xn.x * B0[i] + xn.y * B1[i] + xn.z * B2[i];
            acc[i] = 0.f;
        }
        int e0 = offs[n], e1 = offs[n + 1];
        for (int base = e0; base < e1; base += 64) {
            int ee = base + lane;
            int r = (ee < e1) ? csr_row[ee] : 0;
            float4 q = xpad[r];
            int cnt = e1 - base;
            if (cnt > 64) cnt = 64;
            int t = 0;
            for (; t + 1 < cnt; t += 2) {
                float px0 = bcast_lane(q.x, t),     py0 = bcast_lane(q.y, t),     pz0 = bcast_lane(q.z, t);
                float px1 = bcast_lane(q.x, t + 1), py1 = bcast_lane(q.y, t + 1), pz1 = bcast_lane(q.z, t + 1);
#pragma unroll
                for (int i = 0; i < 5; ++i)
                    acc[i] += fmaxf(va[i] + px0 * A0[i] + py0 * A1[i] + pz0 * A2[i], 0.f);
#pragma unroll
                for (int i = 0; i < 5; ++i)
                    acc[i] += fmaxf(va[i] + px1 * A0[i] + py1 * A1[i] + pz1 * A2[i], 0.f);
            }
            if (t < cnt) {
                float px = bcast_lane(q.x, t), py = bcast_lane(q.y, t), pz = bcast_lane(q.z, t);
#pragma unroll
                for (int i = 0; i < 5; ++i)
                    acc[i] += fmaxf(va[i] + px * A0[i] + py * A1[i] + pz * A2[i], 0.f);
            }
        }
        unsigned int* arow = agg + (unsigned)(n - n_start) * 320 + half * 160 + j;
#pragma unroll
        for (int i = 0; i < 5; ++i) {
            float a = acc[i];
            _Float16 hi = (_Float16)a;
            _Float16 lo = (_Float16)(a - (float)hi);
            half2v pr = {hi, lo};
            arow[i * 32] = __builtin_bit_cast(unsigned int, pr);
        }
    }
}

// Fold via MFMA: xw1[n][:] += agg[n][0:320] @ Mflat[320][32], 16 nodes/wave.
__global__ __launch_bounds__(256) void fold_mfma(
    const unsigned int* __restrict__ agg, const _Float16* __restrict__ MfragG,
    float* __restrict__ xw1, int n_start, int n_end) {
    __shared__ _Float16 Mf[20480];
    {
        const uint4* src = (const uint4*)MfragG;
        uint4* dst = (uint4*)Mf;
        for (int i = threadIdx.x; i < 2560; i += 256) dst[i] = src[i];
    }
    __syncthreads();

    int wave = blockIdx.x * 4 + (threadIdx.x >> 6);
    int lane = threadIdx.x & 63;
    int n0 = n_start + wave * 16;
    if (n0 >= n_end) return;

    int m = lane & 15, q = lane >> 4;
    int arow_n = n0 + m;
    bool rowok = arow_n < n_end;
    const unsigned int* arow = agg + (unsigned)(arow_n - n_start) * 320 + q * 8;

    const half8* mf = (const half8*)Mf;
    f32x4 acc0 = {0.f, 0.f, 0.f, 0.f};
    f32x4 acc1 = {0.f, 0.f, 0.f, 0.f};

    for (int kc = 0; kc < 10; ++kc) {
        half8 ah, al;
        if (rowok) {
            uint4 w0 = *(const uint4*)(arow + kc * 32);
            uint4 w1 = *(const uint4*)(arow + kc * 32 + 4);
            unsigned int w[8] = {w0.x, w0.y, w0.z, w0.w, w1.x, w1.y, w1.z, w1.w};
#pragma unroll
            for (int i = 0; i < 8; ++i) {
                half2v pr = __builtin_bit_cast(half2v, w[i]);
                ah[i] = pr.x;
                al[i] = pr.y;
            }
        } else {
#pragma unroll
            for (int i = 0; i < 8; ++i) { ah[i] = (_Float16)0.f; al[i] = (_Float16)0.f; }
        }
        half8 bh0 = mf[((kc * 2 + 0) * 2 + 0) * 64 + lane];
        half8 bl0 = mf[((kc * 2 + 0) * 2 + 1) * 64 + lane];
        half8 bh1 = mf[((kc * 2 + 1) * 2 + 0) * 64 + lane];
        half8 bl1 = mf[((kc * 2 + 1) * 2 + 1) * 64 + lane];
        acc0 = __builtin_amdgcn_mfma_f32_16x16x32_f16(ah, bh0, acc0, 0, 0, 0);
        acc0 = __builtin_amdgcn_mfma_f32_16x16x32_f16(al, bh0, acc0, 0, 0, 0);
        acc0 = __builtin_amdgcn_mfma_f32_16x16x32_f16(ah, bl0, acc0, 0, 0, 0);
        acc1 = __builtin_amdgcn_mfma_f32_16x16x32_f16(ah, bh1, acc1, 0, 0, 0);
        acc1 = __builtin_amdgcn_mfma_f32_16x16x32_f16(al, bh1, acc1, 0, 0, 0);
        acc1 = __builtin_amdgcn_mfma_f32_16x16x32_f16(ah, bl1, acc1, 0, 0, 0);
    }

    int jcol = lane & 15;
#pragma unroll
    for (int r = 0; r < 4; ++r) {
        int node = n0 + q * 4 + r;
        if (node < n_end) {
            xw1[node * 32 + jcol] += acc0[r];
            xw1[node * 32 + 16 + jcol] += acc1[r];
        }
    }
}

// One node per wave64; half-waves take even/odd CSR slots; dinv[r] is a
// same-address broadcast load (L2-resident 400 KB).
__global__ __launch_bounds__(256, 4) void prop_wave(
    const int* __restrict__ offs, const int* __restrict__ csr_row,
    const float* __restrict__ xw, const float* __restrict__ dinv,
    float* __restrict__ out) {
    int n = blockIdx.x * 4 + (threadIdx.x >> 6);
    if (n >= NN) return;
    int lane = threadIdx.x & 63;
    int j = lane & 31;
    int half = lane >> 5;
    int e0 = offs[n], e1 = offs[n + 1];
    float s0 = 0.f, s1 = 0.f;
    int e = e0 + half;
    for (; e + 2 < e1; e += 4) {
        int r0 = csr_row[e], r1 = csr_row[e + 2];
        s0 += xw[r0 * 32 + j] * dinv[r0];
        s1 += xw[r1 * 32 + j] * dinv[r1];
    }
    if (e < e1) {
        int r = csr_row[e];
        s0 += xw[r * 32 + j] * dinv[r];
    }
    float s = s0 + s1;
    s += __shfl_xor(s, 32, 64);
    if (lane < 32) {
        float di = dinv[n];
        out[n * 32 + j] = di * s + di * di * xw[n * 32 + j];
    }
}

__global__ void xw2_kernel(const float* __restrict__ h1raw, const float* __restrict__ g1b,
                           const float* __restrict__ g2W, float* __restrict__ xw2) {
    int gid = blockIdx.x * 256 + threadIdx.x;
    if (gid >= NN * 32) return;
    int n = gid >> 5, j = gid & 31;
    float s = 0.f;
    for (int k = 0; k < 32; ++k) {
        float h = fmaxf(h1raw[n * 32 + k] + g1b[k], 0.0f);
        s += h * g2W[k * 32 + j];
    }
    xw2[gid] = s;
}

__global__ void pool_seg(const float* __restrict__ h2, const float* __restrict__ g2b,
                         const int* __restrict__ batch, float* __restrict__ pooled,
                         float* __restrict__ counts) {
    int grp = threadIdx.x >> 5, j = threadIdx.x & 31;
    int base = (blockIdx.x * 8 + grp) * 64;
    if (base >= NN) return;
    float bj = g2b[j];
    float acc = 0.f, cnt = 0.f;
    int curg = -1;
    int lim = base + 64;
    if (lim > NN) lim = NN;
    for (int n = base; n < lim; ++n) {
        int g = batch[n];
        if (g != curg) {
            if (curg >= 0) {
                atomicAdd(&pooled[curg * 32 + j], acc);
                if (j == 0) atomicAdd(&counts[curg], cnt);
            }
            curg = g; acc = 0.f; cnt = 0.f;
        }
        acc += fmaxf(h2[n * 32 + j] + bj, 0.f);
        cnt += 1.f;
    }
    if (curg >= 0) {
        atomicAdd(&pooled[curg * 32 + j], acc);
        if (j == 0) atomicAdd(&counts[curg], cnt);
    }
}

__global__ void final_kernel(const float* __restrict__ pooled, const float* __restrict__ counts,
                             const float* __restrict__ clsW, const float* __restrict__ clsb,
                             float* __restrict__ out) {
    int tid = threadIdx.x;
    if (tid >= GG * CC) return;
    int g = tid / CC, cc = tid % CC;
    float inv = 1.0f / fmaxf(counts[g], 1.0f);
    float s = clsb[cc];
    for (int j = 0; j < 32; ++j) s += (pooled[g * 32 + j] * inv) * clsW[j * CC + cc];
    out[g * CC + cc] = s;
}

extern "C" void kernel_launch(void* const* d_in, const int* in_sizes, int n_in,
                              void* d_out, int out_size, void* d_ws, size_t ws_size,
                              hipStream_t stream) {
    const float* x     = (const float*)d_in[0];
    const int*   ei    = (const int*)d_in[1];
    const int*   batch = (const int*)d_in[2];
    const float* fW    = (const float*)d_in[3];
    const float* fb    = (const float*)d_in[4];
    const float* W1    = (const float*)d_in[5];
    const float* b1    = (const float*)d_in[6];
    const float* W2    = (const float*)d_in[7];
    const float* b2    = (const float*)d_in[8];
    const float* g1W   = (const float*)d_in[9];
    const float* g1b   = (const float*)d_in[10];
    const float* g2W   = (const float*)d_in[11];
    const float* g2b   = (const float*)d_in[12];
    const float* clsW  = (const float*)d_in[13];
    const float* clsb  = (const float*)d_in[14];
    float* out = (float*)d_out;

    float4*       xpad    = (float4*)d_ws;                      // 1.6 MB
    unsigned int* agg     = (unsigned int*)(xpad + NN);         // 32 MB
    int*          csr_row = (int*)(agg + (size_t)STRIP * 320);  // 6.4 MB
    int*          rank    = csr_row + NE;                       // 6.4 MB
    int*          ideg    = rank + NE;
    int*          offs    = ideg + NN;
    int*          bsum    = offs + NN + 1;
    float*        dinv    = (float*)(bsum + 512);
    float*        tab     = dinv + NN;
    _Float16*     Mfrag   = (_Float16*)(tab + 16384);           // 20480 halfs
    float*        xw1     = tab + 16384 + 10240;
    float*        U       = xw1 + NN * 32;
    float*        V       = U + NN * 32;
    float*        pooled  = V + NN * 32;
    float*        counts  = pooled + GG * 32;

    const int nodeBlocks = (NN * 32 + 255) / 256;
    const int edgeBlocks = (NE + 255) / 256;
    const int waveBlocks = (NN + 3) / 4;

    zero_int<<<(NN + 255) / 256, 256, 0, stream>>>(ideg, NN);
    zero_f<<<(GG * 33 + 255) / 256, 256, 0, stream>>>(pooled, GG * 33);
    precompute_small<<<10, 1024, 0, stream>>>(fW, fb, W1, b1, W2, b2, g1W, tab);
    mfrag_kernel<<<10, 256, 0, stream>>>(tab, Mfrag);

    deg_rank<<<edgeBlocks, 256, 0, stream>>>(ei, ideg, rank);
    scan_phase1<<<SBLK, 256, 0, stream>>>(ideg, bsum);
    scan_phase2<<<1, 512, 0, stream>>>(bsum);
    scan_phase3<<<SBLK, 256, 0, stream>>>(ideg, bsum, x, offs, dinv, xpad);
    csr_place<<<edgeBlocks, 256, 0, stream>>>(ei, rank, offs, csr_row);

    xw1_init<<<nodeBlocks, 256, 0, stream>>>(x, g1W, ideg, tab, xw1);

    for (int s = 0; s < NN / STRIP; ++s) {
        int ns = s * STRIP, ne2 = ns + STRIP;
        edgeconv_fused<<<2048, 256, 0, stream>>>(xpad, offs, csr_row, tab, agg, ns, ne2);
        int foldWaves = (STRIP + 15) / 16;
        fold_mfma<<<(foldWaves + 3) / 4, 256, 0, stream>>>(agg, Mfrag, xw1, ns, ne2);
    }

    prop_wave<<<waveBlocks, 256, 0, stream>>>(offs, csr_row, xw1, dinv, U);   // h1raw
    xw2_kernel<<<nodeBlocks, 256, 0, stream>>>(U, g1b, g2W, V);               // xw2
    prop_wave<<<waveBlocks, 256, 0, stream>>>(offs, csr_row, V, dinv, xw1);   // h2raw
    pool_seg<<<(NN + 511) / 512, 256, 0, stream>>>(xw1, g2b, batch, pooled, counts);
    final_kernel<<<1, 640, 0, stream>>>(pooled, counts, clsW, clsb, out);
}

// Round 9
// 558.068 us; speedup vs baseline: 6.2068x; 1.0373x over previous
//
#include <hip/hip_runtime.h>

#define NN 100000
#define NE 1600000
#define HH 32
#define CC 10
#define GG 64
#define STRIP 25000
#define SBLK ((NN + 255) / 256)   // 391 scan blocks

typedef _Float16 half8 __attribute__((ext_vector_type(8)));
typedef _Float16 half2v __attribute__((ext_vector_type(2)));
typedef float f32x4 __attribute__((ext_vector_type(4)));

// ---------------- workspace layout ----------------
// float4 xpad[NN]; uint agg[STRIP*320]; int csr_row[NE]; ushort rank[NE];
// int ideg[NN], offs[NN+1], bsum[512]; float dinv[NN], tab[16384];
// _Float16 Mfrag[20480]; _Float16 xh1[NN*32]; float U[NN*32]; _Float16 Vh[NN*32];
// float h2[NN*32], pooled[64*32], counts[64]

__global__ void zero_int(int* p, int n) {
    int i = blockIdx.x * 256 + threadIdx.x;
    if (i < n) p[i] = 0;
}

__global__ void zero_f(float* p, int n) {
    int i = blockIdx.x * 256 + threadIdx.x;
    if (i < n) p[i] = 0.0f;
}

__global__ void precompute_small(const float* __restrict__ fW, const float* __restrict__ fb,
                                 const float* __restrict__ W1, const float* __restrict__ b1,
                                 const float* __restrict__ W2, const float* __restrict__ b2,
                                 const float* __restrict__ g1W, float* __restrict__ tab) {
    int c = blockIdx.x;
    int k = threadIdx.x >> 5;
    int j = threadIdx.x & 31;
    float m = 0.f;
    for (int mm = 0; mm < 32; ++mm)
        m += W2[k * 32 + mm] * g1W[(3 + 32 * c + mm) * 32 + j];
    tab[2240 + c * 1024 + k * 32 + j] = m;

    if (k < 3) {
        float a = 0.f, b = 0.f;
        for (int i = 0; i < 32; ++i) {
            float w = fW[c * 96 + k * 32 + i];
            a += w * W1[i * 32 + j];
            b += w * W1[(32 + i) * 32 + j];
        }
        tab[c * 96 + k * 32 + j] = a;
        tab[960 + c * 96 + k * 32 + j] = b;
    } else if (k == 3) {
        float h = b1[j];
        for (int i = 0; i < 32; ++i)
            h += fb[c * 32 + i] * (W1[i * 32 + j] + W1[(32 + i) * 32 + j]);
        tab[1920 + c * 32 + j] = h;
    } else if (k == 4 && c == 0) {
        float t = 0.f;
        for (int cc2 = 0; cc2 < CC; ++cc2)
            for (int mm = 0; mm < 32; ++mm)
                t += b2[mm] * g1W[(3 + 32 * cc2 + mm) * 32 + j];
        tab[12480 + j] = t;
    }
}

// Pre-swizzle Mflat[320][32] into MFMA B-fragment order, fp16 hi/lo planes.
__global__ void mfrag_kernel(const float* __restrict__ tab, _Float16* __restrict__ Mfrag) {
    int gid = blockIdx.x * 256 + threadIdx.x;   // [0, 2560)
    if (gid >= 2560) return;
    int set = gid >> 6, l = gid & 63;
    int p = set & 1, jt = (set >> 1) & 1, kc = set >> 2;
    int j = jt * 16 + (l & 15);
    int kbase = kc * 32 + (l >> 4) * 8;
#pragma unroll
    for (int i = 0; i < 8; ++i) {
        float v = tab[2240 + (kbase + i) * 32 + j];
        _Float16 hi = (_Float16)v;
        Mfrag[gid * 8 + i] = p ? (_Float16)(v - (float)hi) : hi;
    }
}

// degree count + per-edge rank (arrival order within destination)
__global__ void deg_rank(const int* __restrict__ ei, int* __restrict__ ideg,
                         unsigned short* __restrict__ rank) {
    int e = blockIdx.x * 256 + threadIdx.x;
    if (e < NE) rank[e] = (unsigned short)atomicAdd(&ideg[ei[NE + e]], 1);
}

// -------- hierarchical scan --------
__global__ void scan_phase1(const int* __restrict__ ideg, int* __restrict__ bsum) {
    __shared__ int sh[256];
    int b = blockIdx.x, t = threadIdx.x;
    int i = b * 256 + t;
    sh[t] = (i < NN) ? ideg[i] : 0;
    __syncthreads();
    for (int off = 128; off > 0; off >>= 1) {
        if (t < off) sh[t] += sh[t + off];
        __syncthreads();
    }
    if (t == 0) bsum[b] = sh[0];
}

__global__ void scan_phase2(int* __restrict__ bsum) {
    __shared__ int sh[512];
    int t = threadIdx.x;
    int v = (t < SBLK) ? bsum[t] : 0;
    sh[t] = v;
    __syncthreads();
    for (int off = 1; off < 512; off <<= 1) {
        int add = (t >= off) ? sh[t - off] : 0;
        __syncthreads();
        sh[t] += add;
        __syncthreads();
    }
    if (t < SBLK) bsum[t] = sh[t] - v;   // exclusive
}

// phase3: per-block scan + offset; fills offs/dinv/xpad
__global__ void scan_phase3(const int* __restrict__ ideg, const int* __restrict__ bsum,
                            const float* __restrict__ x, int* __restrict__ offs,
                            float* __restrict__ dinv, float4* __restrict__ xpad) {
    __shared__ int sh[256];
    int b = blockIdx.x, t = threadIdx.x;
    int i = b * 256 + t;
    int v = (i < NN) ? ideg[i] : 0;
    sh[t] = v;
    __syncthreads();
    for (int off = 1; off < 256; off <<= 1) {
        int add = (t >= off) ? sh[t - off] : 0;
        __syncthreads();
        sh[t] += add;
        __syncthreads();
    }
    int excl = sh[t] - v + bsum[b];
    if (i < NN) {
        offs[i] = excl;
        float di = rsqrtf((float)v + 1.0f);
        dinv[i] = di;
        xpad[i] = make_float4(x[i * 3], x[i * 3 + 1], x[i * 3 + 2], di);
    }
    if (i == NN - 1) offs[NN] = excl + v;
}

// CSR place: no atomics — pos = offs[col] + rank[e]; 4 B scatter
__global__ void csr_place(const int* __restrict__ ei, const unsigned short* __restrict__ rank,
                          const int* __restrict__ offs, int* __restrict__ csr_row) {
    int e = blockIdx.x * 256 + threadIdx.x;
    if (e < NE) {
        int r = ei[e];
        int c = ei[NE + e];
        csr_row[offs[c] + (int)rank[e]] = r;
    }
}

__device__ __forceinline__ float bcast_lane(float v, int t) {
    return __uint_as_float(__builtin_amdgcn_readlane(__float_as_uint(v), (unsigned)t));
}

// Edge phase: one node per wave, halves take classes 0-4 / 5-9.
// Lane-parallel csr_row load (coalesced), gather xpad[r] (L2-resident),
// broadcast via v_readlane. Writes agg packed (fp16 hi | fp16 lo).
__global__ __launch_bounds__(256, 8) void edgeconv_fused(
    const float4* __restrict__ xpad, const int* __restrict__ offs,
    const int* __restrict__ csr_row, const float* __restrict__ tab,
    unsigned int* __restrict__ agg, int n_start, int n_end) {
    int lane = threadIdx.x & 63;
    int j = lane & 31;
    int half = lane >> 5;
    int c0 = half * 5;

    float A0[5], A1[5], A2[5], B0[5], B1[5], B2[5], hb[5];
#pragma unroll
    for (int i = 0; i < 5; ++i) {
        int cb = (c0 + i) * 96;
        A0[i] = tab[cb + j];       A1[i] = tab[cb + 32 + j];       A2[i] = tab[cb + 64 + j];
        B0[i] = tab[960 + cb + j]; B1[i] = tab[960 + cb + 32 + j]; B2[i] = tab[960 + cb + 64 + j];
        hb[i] = tab[1920 + (c0 + i) * 32 + j];
    }

    int wid = blockIdx.x * 4 + (threadIdx.x >> 6);
    const int wstride = gridDim.x * 4;

    for (int n = n_start + wid; n < n_end; n += wstride) {
        float4 xn = xpad[n];
        float va[5], acc[5];
#pragma unroll
        for (int i = 0; i < 5; ++i) {
            va[i] = hb[i] + xn.x * B0[i] + xn.y * B1[i] + xn.z * B2[i];
            acc[i] = 0.f;
        }
        int e0 = offs[n], e1 = offs[n + 1];
        for (int base = e0; base < e1; base += 64) {
            int ee = base + lane;
            int r = (ee < e1) ? csr_row[ee] : 0;
            float4 q = xpad[r];
            int cnt = e1 - base;
            if (cnt > 64) cnt = 64;
            int t = 0;
            for (; t + 1 < cnt; t += 2) {
                float px0 = bcast_lane(q.x, t),     py0 = bcast_lane(q.y, t),     pz0 = bcast_lane(q.z, t);
                float px1 = bcast_lane(q.x, t + 1), py1 = bcast_lane(q.y, t + 1), pz1 = bcast_lane(q.z, t + 1);
#pragma unroll
                for (int i = 0; i < 5; ++i)
                    acc[i] += fmaxf(va[i] + px0 * A0[i] + py0 * A1[i] + pz0 * A2[i], 0.f);
#pragma unroll
                for (int i = 0; i < 5; ++i)
                    acc[i] += fmaxf(va[i] + px1 * A0[i] + py1 * A1[i] + pz1 * A2[i], 0.f);
            }
            if (t < cnt) {
                float px = bcast_lane(q.x, t), py = bcast_lane(q.y, t), pz = bcast_lane(q.z, t);
#pragma unroll
                for (int i = 0; i < 5; ++i)
                    acc[i] += fmaxf(va[i] + px * A0[i] + py * A1[i] + pz * A2[i], 0.f);
            }
        }
        unsigned int* arow = agg + (unsigned)(n - n_start) * 320 + half * 160 + j;
#pragma unroll
        for (int i = 0; i < 5; ++i) {
            float a = acc[i];
            _Float16 hi = (_Float16)a;
            _Float16 lo = (_Float16)(a - (float)hi);
            half2v pr = {hi, lo};
            arow[i * 32] = __builtin_bit_cast(unsigned int, pr);
        }
    }
}

// Fold via MFMA + fused xw1-init epilogue; writes fp16 xh1 directly.
__global__ __launch_bounds__(256) void fold_mfma(
    const unsigned int* __restrict__ agg, const _Float16* __restrict__ MfragG,
    const float4* __restrict__ xpad, const int* __restrict__ ideg,
    const float* __restrict__ tab, const float* __restrict__ g1W,
    _Float16* __restrict__ xh1, int n_start, int n_end) {
    __shared__ _Float16 Mf[20480];
    {
        const uint4* src = (const uint4*)MfragG;
        uint4* dst = (uint4*)Mf;
        for (int i = threadIdx.x; i < 2560; i += 256) dst[i] = src[i];
    }
    __syncthreads();

    int wave = blockIdx.x * 4 + (threadIdx.x >> 6);
    int lane = threadIdx.x & 63;
    int n0 = n_start + wave * 16;
    if (n0 >= n_end) return;

    int m = lane & 15, q = lane >> 4;
    int arow_n = n0 + m;
    bool rowok = arow_n < n_end;
    const unsigned int* arow = agg + (unsigned)(arow_n - n_start) * 320 + q * 8;

    const half8* mf = (const half8*)Mf;
    f32x4 acc0 = {0.f, 0.f, 0.f, 0.f};
    f32x4 acc1 = {0.f, 0.f, 0.f, 0.f};

    for (int kc = 0; kc < 10; ++kc) {
        half8 ah, al;
        if (rowok) {
            uint4 w0 = *(const uint4*)(arow + kc * 32);
            uint4 w1 = *(const uint4*)(arow + kc * 32 + 4);
            unsigned int w[8] = {w0.x, w0.y, w0.z, w0.w, w1.x, w1.y, w1.z, w1.w};
#pragma unroll
            for (int i = 0; i < 8; ++i) {
                half2v pr = __builtin_bit_cast(half2v, w[i]);
                ah[i] = pr.x;
                al[i] = pr.y;
            }
        } else {
#pragma unroll
            for (int i = 0; i < 8; ++i) { ah[i] = (_Float16)0.f; al[i] = (_Float16)0.f; }
        }
        half8 bh0 = mf[((kc * 2 + 0) * 2 + 0) * 64 + lane];
        half8 bl0 = mf[((kc * 2 + 0) * 2 + 1) * 64 + lane];
        half8 bh1 = mf[((kc * 2 + 1) * 2 + 0) * 64 + lane];
        half8 bl1 = mf[((kc * 2 + 1) * 2 + 1) * 64 + lane];
        acc0 = __builtin_amdgcn_mfma_f32_16x16x32_f16(ah, bh0, acc0, 0, 0, 0);
        acc0 = __builtin_amdgcn_mfma_f32_16x16x32_f16(al, bh0, acc0, 0, 0, 0);
        acc0 = __builtin_amdgcn_mfma_f32_16x16x32_f16(ah, bl0, acc0, 0, 0, 0);
        acc1 = __builtin_amdgcn_mfma_f32_16x16x32_f16(ah, bh1, acc1, 0, 0, 0);
        acc1 = __builtin_amdgcn_mfma_f32_16x16x32_f16(al, bh1, acc1, 0, 0, 0);
        acc1 = __builtin_amdgcn_mfma_f32_16x16x32_f16(ah, bl1, acc1, 0, 0, 0);
    }

    int jcol = lane & 15;
    float t0 = tab[12480 + jcol],      t1 = tab[12480 + 16 + jcol];
    float w00 = g1W[jcol],      w01 = g1W[32 + jcol],      w02 = g1W[64 + jcol];
    float w10 = g1W[16 + jcol], w11 = g1W[48 + jcol],      w12 = g1W[80 + jcol];
#pragma unroll
    for (int r = 0; r < 4; ++r) {
        int node = n0 + q * 4 + r;
        if (node < n_end) {
            float4 xn = xpad[node];
            float dg = (float)ideg[node];
            float v0 = dg * t0 + xn.x * w00 + xn.y * w01 + xn.z * w02 + acc0[r];
            float v1 = dg * t1 + xn.x * w10 + xn.y * w11 + xn.z * w12 + acc1[r];
            xh1[node * 32 + jcol]      = (_Float16)v0;
            xh1[node * 32 + 16 + jcol] = (_Float16)v1;
        }
    }
}

// One node per wave64; half-waves take even/odd CSR slots; fp16 gather input,
// fp32 output. dinv[r] broadcast-ish from L2-resident 400 KB.
__global__ __launch_bounds__(256, 4) void prop_wave(
    const int* __restrict__ offs, const int* __restrict__ csr_row,
    const _Float16* __restrict__ xh, const float* __restrict__ dinv,
    float* __restrict__ out) {
    int n = blockIdx.x * 4 + (threadIdx.x >> 6);
    if (n >= NN) return;
    int lane = threadIdx.x & 63;
    int j = lane & 31;
    int half = lane >> 5;
    int e0 = offs[n], e1 = offs[n + 1];
    float s0 = 0.f, s1 = 0.f;
    int e = e0 + half;
    for (; e + 2 < e1; e += 4) {
        int r0 = csr_row[e], r1 = csr_row[e + 2];
        s0 += (float)xh[r0 * 32 + j] * dinv[r0];
        s1 += (float)xh[r1 * 32 + j] * dinv[r1];
    }
    if (e < e1) {
        int r = csr_row[e];
        s0 += (float)xh[r * 32 + j] * dinv[r];
    }
    float s = s0 + s1;
    s += __shfl_xor(s, 32, 64);
    if (lane < 32) {
        float di = dinv[n];
        out[n * 32 + j] = di * s + di * di * (float)xh[n * 32 + j];
    }
}

// xw2: reads fp32 h1raw, writes fp16 Vh = relu(h1+b1) @ g2W
__global__ void xw2_kernel(const float* __restrict__ h1raw, const float* __restrict__ g1b,
                           const float* __restrict__ g2W, _Float16* __restrict__ Vh) {
    int gid = blockIdx.x * 256 + threadIdx.x;
    if (gid >= NN * 32) return;
    int n = gid >> 5, j = gid & 31;
    float s = 0.f;
    for (int k = 0; k < 32; ++k) {
        float h = fmaxf(h1raw[n * 32 + k] + g1b[k], 0.0f);
        s += h * g2W[k * 32 + j];
    }
    Vh[gid] = (_Float16)s;
}

__global__ void pool_seg(const float* __restrict__ h2, const float* __restrict__ g2b,
                         const int* __restrict__ batch, float* __restrict__ pooled,
                         float* __restrict__ counts) {
    int grp = threadIdx.x >> 5, j = threadIdx.x & 31;
    int base = (blockIdx.x * 8 + grp) * 64;
    if (base >= NN) return;
    float bj = g2b[j];
    float acc = 0.f, cnt = 0.f;
    int curg = -1;
    int lim = base + 64;
    if (lim > NN) lim = NN;
    for (int n = base; n < lim; ++n) {
        int g = batch[n];
        if (g != curg) {
            if (curg >= 0) {
                atomicAdd(&pooled[curg * 32 + j], acc);
                if (j == 0) atomicAdd(&counts[curg], cnt);
            }
            curg = g; acc = 0.f; cnt = 0.f;
        }
        acc += fmaxf(h2[n * 32 + j] + bj, 0.f);
        cnt += 1.f;
    }
    if (curg >= 0) {
        atomicAdd(&pooled[curg * 32 + j], acc);
        if (j == 0) atomicAdd(&counts[curg], cnt);
    }
}

__global__ void final_kernel(const float* __restrict__ pooled, const float* __restrict__ counts,
                             const float* __restrict__ clsW, const float* __restrict__ clsb,
                             float* __restrict__ out) {
    int tid = threadIdx.x;
    if (tid >= GG * CC) return;
    int g = tid / CC, cc = tid % CC;
    float inv = 1.0f / fmaxf(counts[g], 1.0f);
    float s = clsb[cc];
    for (int j = 0; j < 32; ++j) s += (pooled[g * 32 + j] * inv) * clsW[j * CC + cc];
    out[g * CC + cc] = s;
}

extern "C" void kernel_launch(void* const* d_in, const int* in_sizes, int n_in,
                              void* d_out, int out_size, void* d_ws, size_t ws_size,
                              hipStream_t stream) {
    const float* x     = (const float*)d_in[0];
    const int*   ei    = (const int*)d_in[1];
    const int*   batch = (const int*)d_in[2];
    const float* fW    = (const float*)d_in[3];
    const float* fb    = (const float*)d_in[4];
    const float* W1    = (const float*)d_in[5];
    const float* b1    = (const float*)d_in[6];
    const float* W2    = (const float*)d_in[7];
    const float* b2    = (const float*)d_in[8];
    const float* g1W   = (const float*)d_in[9];
    const float* g1b   = (const float*)d_in[10];
    const float* g2W   = (const float*)d_in[11];
    const float* g2b   = (const float*)d_in[12];
    const float* clsW  = (const float*)d_in[13];
    const float* clsb  = (const float*)d_in[14];
    float* out = (float*)d_out;

    float4*         xpad    = (float4*)d_ws;                       // 1.6 MB
    unsigned int*   agg     = (unsigned int*)(xpad + NN);          // 32 MB
    int*            csr_row = (int*)(agg + (size_t)STRIP * 320);   // 6.4 MB
    unsigned short* rank    = (unsigned short*)(csr_row + NE);     // 3.2 MB
    int*            ideg    = (int*)(rank + NE);
    int*            offs    = ideg + NN;
    int*            bsum    = offs + NN + 1;
    float*          dinv    = (float*)(bsum + 512);
    float*          tab     = dinv + NN;
    _Float16*       Mfrag   = (_Float16*)(tab + 16384);            // 40 KB
    _Float16*       xh1     = Mfrag + 20480;                       // 6.4 MB
    float*          U       = (float*)(xh1 + (size_t)NN * 32);     // 12.8 MB (h1raw)
    _Float16*       Vh      = (_Float16*)(U + (size_t)NN * 32);    // 6.4 MB
    float*          h2      = (float*)(Vh + (size_t)NN * 32);      // 12.8 MB
    float*          pooled  = h2 + (size_t)NN * 32;
    float*          counts  = pooled + GG * 32;

    const int nodeBlocks = (NN * 32 + 255) / 256;
    const int edgeBlocks = (NE + 255) / 256;
    const int waveBlocks = (NN + 3) / 4;

    zero_int<<<(NN + 255) / 256, 256, 0, stream>>>(ideg, NN);
    zero_f<<<(GG * 33 + 255) / 256, 256, 0, stream>>>(pooled, GG * 33);
    precompute_small<<<10, 1024, 0, stream>>>(fW, fb, W1, b1, W2, b2, g1W, tab);
    mfrag_kernel<<<10, 256, 0, stream>>>(tab, Mfrag);

    deg_rank<<<edgeBlocks, 256, 0, stream>>>(ei, ideg, rank);
    scan_phase1<<<SBLK, 256, 0, stream>>>(ideg, bsum);
    scan_phase2<<<1, 512, 0, stream>>>(bsum);
    scan_phase3<<<SBLK, 256, 0, stream>>>(ideg, bsum, x, offs, dinv, xpad);
    csr_place<<<edgeBlocks, 256, 0, stream>>>(ei, rank, offs, csr_row);

    for (int s = 0; s < NN / STRIP; ++s) {
        int ns = s * STRIP, ne2 = ns + STRIP;
        edgeconv_fused<<<2048, 256, 0, stream>>>(xpad, offs, csr_row, tab, agg, ns, ne2);
        int foldWaves = (STRIP + 15) / 16;
        fold_mfma<<<(foldWaves + 3) / 4, 256, 0, stream>>>(agg, Mfrag, xpad, ideg, tab, g1W,
                                                           xh1, ns, ne2);
    }

    prop_wave<<<waveBlocks, 256, 0, stream>>>(offs, csr_row, xh1, dinv, U);   // h1raw
    xw2_kernel<<<nodeBlocks, 256, 0, stream>>>(U, g1b, g2W, Vh);              // xw2 fp16
    prop_wave<<<waveBlocks, 256, 0, stream>>>(offs, csr_row, Vh, dinv, h2);   // h2raw
    pool_seg<<<(NN + 511) / 512, 256, 0, stream>>>(h2, g2b, batch, pooled, counts);
    final_kernel<<<1, 640, 0, stream>>>(pooled, counts, clsW, clsb, out);
}

// Round 10
// 555.795 us; speedup vs baseline: 6.2322x; 1.0041x over previous
//
#include <hip/hip_runtime.h>

#define NN 100000
#define NE 1600000
#define HH 32
#define CC 10
#define GG 64
#define STRIP 25000
#define SBLK ((NN + 255) / 256)   // 391 scan blocks

typedef _Float16 half8 __attribute__((ext_vector_type(8)));
typedef _Float16 half2v __attribute__((ext_vector_type(2)));
typedef float f32x4 __attribute__((ext_vector_type(4)));

// ---------------- workspace layout ----------------
// float4 xpad[NN]; uint agg[STRIP*320]; int csr_row[NE]; ushort rank[NE];
// int cnt[8*NN] (histogram copies -> bases), ideg[NN], offs[NN+1], bsum[512];
// float dinv[NN], tab[16384]; _Float16 Mfrag[20480]; _Float16 xh1[NN*32];
// float U[NN*32]; _Float16 Vh[NN*32]; float h2[NN*32], pooled, counts

__device__ __forceinline__ int xcc_id() {
    int x;
    asm volatile("s_getreg_b32 %0, hwreg(HW_REG_XCC_ID)" : "=s"(x));
    return x & 7;
}

__global__ void zero_int(int* p, int n) {
    int i = blockIdx.x * 256 + threadIdx.x;
    if (i < n) p[i] = 0;
}

__global__ void zero_f(float* p, int n) {
    int i = blockIdx.x * 256 + threadIdx.x;
    if (i < n) p[i] = 0.0f;
}

__global__ void precompute_small(const float* __restrict__ fW, const float* __restrict__ fb,
                                 const float* __restrict__ W1, const float* __restrict__ b1,
                                 const float* __restrict__ W2, const float* __restrict__ b2,
                                 const float* __restrict__ g1W, float* __restrict__ tab) {
    int c = blockIdx.x;
    int k = threadIdx.x >> 5;
    int j = threadIdx.x & 31;
    float m = 0.f;
    for (int mm = 0; mm < 32; ++mm)
        m += W2[k * 32 + mm] * g1W[(3 + 32 * c + mm) * 32 + j];
    tab[2240 + c * 1024 + k * 32 + j] = m;

    if (k < 3) {
        float a = 0.f, b = 0.f;
        for (int i = 0; i < 32; ++i) {
            float w = fW[c * 96 + k * 32 + i];
            a += w * W1[i * 32 + j];
            b += w * W1[(32 + i) * 32 + j];
        }
        tab[c * 96 + k * 32 + j] = a;
        tab[960 + c * 96 + k * 32 + j] = b;
    } else if (k == 3) {
        float h = b1[j];
        for (int i = 0; i < 32; ++i)
            h += fb[c * 32 + i] * (W1[i * 32 + j] + W1[(32 + i) * 32 + j]);
        tab[1920 + c * 32 + j] = h;
    } else if (k == 4 && c == 0) {
        float t = 0.f;
        for (int cc2 = 0; cc2 < CC; ++cc2)
            for (int mm = 0; mm < 32; ++mm)
                t += b2[mm] * g1W[(3 + 32 * cc2 + mm) * 32 + j];
        tab[12480 + j] = t;
    }
}

// Pre-swizzle Mflat[320][32] into MFMA B-fragment order, fp16 hi/lo planes.
__global__ void mfrag_kernel(const float* __restrict__ tab, _Float16* __restrict__ Mfrag) {
    int gid = blockIdx.x * 256 + threadIdx.x;   // [0, 2560)
    if (gid >= 2560) return;
    int set = gid >> 6, l = gid & 63;
    int p = set & 1, jt = (set >> 1) & 1, kc = set >> 2;
    int j = jt * 16 + (l & 15);
    int kbase = kc * 32 + (l >> 4) * 8;
#pragma unroll
    for (int i = 0; i < 8; ++i) {
        float v = tab[2240 + (kbase + i) * 32 + j];
        _Float16 hi = (_Float16)v;
        Mfrag[gid * 8 + i] = p ? (_Float16)(v - (float)hi) : hi;
    }
}

// XCD-privatized degree/rank: atomics into cnt[xcc][col] stay in the local L2
// (no cross-XCD line migration). rank packs (local<<3)|copy; correct for ANY
// copy assignment — xcc only affects locality, not correctness.
__global__ void deg_rank(const int* __restrict__ ei, int* __restrict__ cnt,
                         unsigned short* __restrict__ rank) {
    int e = blockIdx.x * 256 + threadIdx.x;
    int xcc = xcc_id();
    if (e < NE) {
        int c = ei[NE + e];
        int local = atomicAdd(&cnt[xcc * NN + c], 1);
        rank[e] = (unsigned short)((local << 3) | xcc);
    }
}

// -------- hierarchical scan --------
// phase1: ideg[n] = sum of 8 copies; per-block sums for the scan
__global__ void scan_phase1(const int* __restrict__ cnt, int* __restrict__ ideg,
                            int* __restrict__ bsum) {
    __shared__ int sh[256];
    int b = blockIdx.x, t = threadIdx.x;
    int i = b * 256 + t;
    int s = 0;
    if (i < NN) {
#pragma unroll
        for (int c = 0; c < 8; ++c) s += cnt[c * NN + i];
        ideg[i] = s;
    }
    sh[t] = s;
    __syncthreads();
    for (int off = 128; off > 0; off >>= 1) {
        if (t < off) sh[t] += sh[t + off];
        __syncthreads();
    }
    if (t == 0) bsum[b] = sh[0];
}

__global__ void scan_phase2(int* __restrict__ bsum) {
    __shared__ int sh[512];
    int t = threadIdx.x;
    int v = (t < SBLK) ? bsum[t] : 0;
    sh[t] = v;
    __syncthreads();
    for (int off = 1; off < 512; off <<= 1) {
        int add = (t >= off) ? sh[t - off] : 0;
        __syncthreads();
        sh[t] += add;
        __syncthreads();
    }
    if (t < SBLK) bsum[t] = sh[t] - v;   // exclusive
}

// phase3: per-block scan + offset; fills offs/dinv/xpad and converts cnt
// copies into exclusive per-copy bases (in place).
__global__ void scan_phase3(const int* __restrict__ ideg, const int* __restrict__ bsum,
                            const float* __restrict__ x, int* __restrict__ offs,
                            float* __restrict__ dinv, float4* __restrict__ xpad,
                            int* __restrict__ cnt) {
    __shared__ int sh[256];
    int b = blockIdx.x, t = threadIdx.x;
    int i = b * 256 + t;
    int v = (i < NN) ? ideg[i] : 0;
    sh[t] = v;
    __syncthreads();
    for (int off = 1; off < 256; off <<= 1) {
        int add = (t >= off) ? sh[t - off] : 0;
        __syncthreads();
        sh[t] += add;
        __syncthreads();
    }
    int excl = sh[t] - v + bsum[b];
    if (i < NN) {
        offs[i] = excl;
        int run = excl;
#pragma unroll
        for (int c = 0; c < 8; ++c) {
            int cc = cnt[c * NN + i];
            cnt[c * NN + i] = run;
            run += cc;
        }
        float di = rsqrtf((float)v + 1.0f);
        dinv[i] = di;
        xpad[i] = make_float4(x[i * 3], x[i * 3 + 1], x[i * 3 + 2], di);
    }
    if (i == NN - 1) offs[NN] = excl + v;
}

// CSR place: no atomics — pos = base[copy][col] + local; 4 B scatter
__global__ void csr_place(const int* __restrict__ ei, const unsigned short* __restrict__ rank,
                          const int* __restrict__ cnt, int* __restrict__ csr_row) {
    int e = blockIdx.x * 256 + threadIdx.x;
    if (e < NE) {
        int r = ei[e];
        int c = ei[NE + e];
        int rk = rank[e];
        csr_row[cnt[(rk & 7) * NN + c] + (rk >> 3)] = r;
    }
}

__device__ __forceinline__ float bcast_lane(float v, int t) {
    return __uint_as_float(__builtin_amdgcn_readlane(__float_as_uint(v), (unsigned)t));
}

// Edge phase: one node per wave, halves take classes 0-4 / 5-9.
__global__ __launch_bounds__(256, 8) void edgeconv_fused(
    const float4* __restrict__ xpad, const int* __restrict__ offs,
    const int* __restrict__ csr_row, const float* __restrict__ tab,
    unsigned int* __restrict__ agg, int n_start, int n_end) {
    int lane = threadIdx.x & 63;
    int j = lane & 31;
    int half = lane >> 5;
    int c0 = half * 5;

    float A0[5], A1[5], A2[5], B0[5], B1[5], B2[5], hb[5];
#pragma unroll
    for (int i = 0; i < 5; ++i) {
        int cb = (c0 + i) * 96;
        A0[i] = tab[cb + j];       A1[i] = tab[cb + 32 + j];       A2[i] = tab[cb + 64 + j];
        B0[i] = tab[960 + cb + j]; B1[i] = tab[960 + cb + 32 + j]; B2[i] = tab[960 + cb + 64 + j];
        hb[i] = tab[1920 + (c0 + i) * 32 + j];
    }

    int wid = blockIdx.x * 4 + (threadIdx.x >> 6);
    const int wstride = gridDim.x * 4;

    for (int n = n_start + wid; n < n_end; n += wstride) {
        float4 xn = xpad[n];
        float va[5], acc[5];
#pragma unroll
        for (int i = 0; i < 5; ++i) {
            va[i] = hb[i] + xn.x * B0[i] + xn.y * B1[i] + xn.z * B2[i];
            acc[i] = 0.f;
        }
        int e0 = offs[n], e1 = offs[n + 1];
        for (int base = e0; base < e1; base += 64) {
            int ee = base + lane;
            int r = (ee < e1) ? csr_row[ee] : 0;
            float4 q = xpad[r];
            int cnt2 = e1 - base;
            if (cnt2 > 64) cnt2 = 64;
            int t = 0;
            for (; t + 1 < cnt2; t += 2) {
                float px0 = bcast_lane(q.x, t),     py0 = bcast_lane(q.y, t),     pz0 = bcast_lane(q.z, t);
                float px1 = bcast_lane(q.x, t + 1), py1 = bcast_lane(q.y, t + 1), pz1 = bcast_lane(q.z, t + 1);
#pragma unroll
                for (int i = 0; i < 5; ++i)
                    acc[i] += fmaxf(va[i] + px0 * A0[i] + py0 * A1[i] + pz0 * A2[i], 0.f);
#pragma unroll
                for (int i = 0; i < 5; ++i)
                    acc[i] += fmaxf(va[i] + px1 * A0[i] + py1 * A1[i] + pz1 * A2[i], 0.f);
            }
            if (t < cnt2) {
                float px = bcast_lane(q.x, t), py = bcast_lane(q.y, t), pz = bcast_lane(q.z, t);
#pragma unroll
                for (int i = 0; i < 5; ++i)
                    acc[i] += fmaxf(va[i] + px * A0[i] + py * A1[i] + pz * A2[i], 0.f);
            }
        }
        unsigned int* arow = agg + (unsigned)(n - n_start) * 320 + half * 160 + j;
#pragma unroll
        for (int i = 0; i < 5; ++i) {
            float a = acc[i];
            _Float16 hi = (_Float16)a;
            _Float16 lo = (_Float16)(a - (float)hi);
            half2v pr = {hi, lo};
            arow[i * 32] = __builtin_bit_cast(unsigned int, pr);
        }
    }
}

// Fold via MFMA + fused xw1-init epilogue; writes fp16 xh1 directly.
__global__ __launch_bounds__(256) void fold_mfma(
    const unsigned int* __restrict__ agg, const _Float16* __restrict__ MfragG,
    const float4* __restrict__ xpad, const int* __restrict__ ideg,
    const float* __restrict__ tab, const float* __restrict__ g1W,
    _Float16* __restrict__ xh1, int n_start, int n_end) {
    __shared__ _Float16 Mf[20480];
    {
        const uint4* src = (const uint4*)MfragG;
        uint4* dst = (uint4*)Mf;
        for (int i = threadIdx.x; i < 2560; i += 256) dst[i] = src[i];
    }
    __syncthreads();

    int wave = blockIdx.x * 4 + (threadIdx.x >> 6);
    int lane = threadIdx.x & 63;
    int n0 = n_start + wave * 16;
    if (n0 >= n_end) return;

    int m = lane & 15, q = lane >> 4;
    int arow_n = n0 + m;
    bool rowok = arow_n < n_end;
    const unsigned int* arow = agg + (unsigned)(arow_n - n_start) * 320 + q * 8;

    const half8* mf = (const half8*)Mf;
    f32x4 acc0 = {0.f, 0.f, 0.f, 0.f};
    f32x4 acc1 = {0.f, 0.f, 0.f, 0.f};

    for (int kc = 0; kc < 10; ++kc) {
        half8 ah, al;
        if (rowok) {
            uint4 w0 = *(const uint4*)(arow + kc * 32);
            uint4 w1 = *(const uint4*)(arow + kc * 32 + 4);
            unsigned int w[8] = {w0.x, w0.y, w0.z, w0.w, w1.x, w1.y, w1.z, w1.w};
#pragma unroll
            for (int i = 0; i < 8; ++i) {
                half2v pr = __builtin_bit_cast(half2v, w[i]);
                ah[i] = pr.x;
                al[i] = pr.y;
            }
        } else {
#pragma unroll
            for (int i = 0; i < 8; ++i) { ah[i] = (_Float16)0.f; al[i] = (_Float16)0.f; }
        }
        half8 bh0 = mf[((kc * 2 + 0) * 2 + 0) * 64 + lane];
        half8 bl0 = mf[((kc * 2 + 0) * 2 + 1) * 64 + lane];
        half8 bh1 = mf[((kc * 2 + 1) * 2 + 0) * 64 + lane];
        half8 bl1 = mf[((kc * 2 + 1) * 2 + 1) * 64 + lane];
        acc0 = __builtin_amdgcn_mfma_f32_16x16x32_f16(ah, bh0, acc0, 0, 0, 0);
        acc0 = __builtin_amdgcn_mfma_f32_16x16x32_f16(al, bh0, acc0, 0, 0, 0);
        acc0 = __builtin_amdgcn_mfma_f32_16x16x32_f16(ah, bl0, acc0, 0, 0, 0);
        acc1 = __builtin_amdgcn_mfma_f32_16x16x32_f16(ah, bh1, acc1, 0, 0, 0);
        acc1 = __builtin_amdgcn_mfma_f32_16x16x32_f16(al, bh1, acc1, 0, 0, 0);
        acc1 = __builtin_amdgcn_mfma_f32_16x16x32_f16(ah, bl1, acc1, 0, 0, 0);
    }

    int jcol = lane & 15;
    float t0 = tab[12480 + jcol],      t1 = tab[12480 + 16 + jcol];
    float w00 = g1W[jcol],      w01 = g1W[32 + jcol],      w02 = g1W[64 + jcol];
    float w10 = g1W[16 + jcol], w11 = g1W[48 + jcol],      w12 = g1W[80 + jcol];
#pragma unroll
    for (int r = 0; r < 4; ++r) {
        int node = n0 + q * 4 + r;
        if (node < n_end) {
            float4 xn = xpad[node];
            float dg = (float)ideg[node];
            float v0 = dg * t0 + xn.x * w00 + xn.y * w01 + xn.z * w02 + acc0[r];
            float v1 = dg * t1 + xn.x * w10 + xn.y * w11 + xn.z * w12 + acc1[r];
            xh1[node * 32 + jcol]      = (_Float16)v0;
            xh1[node * 32 + 16 + jcol] = (_Float16)v1;
        }
    }
}

// One node per wave64; half-waves take even/odd CSR slots; fp16 gather input.
__global__ __launch_bounds__(256, 4) void prop_wave(
    const int* __restrict__ offs, const int* __restrict__ csr_row,
    const _Float16* __restrict__ xh, const float* __restrict__ dinv,
    float* __restrict__ out) {
    int n = blockIdx.x * 4 + (threadIdx.x >> 6);
    if (n >= NN) return;
    int lane = threadIdx.x & 63;
    int j = lane & 31;
    int half = lane >> 5;
    int e0 = offs[n], e1 = offs[n + 1];
    float s0 = 0.f, s1 = 0.f;
    int e = e0 + half;
    for (; e + 2 < e1; e += 4) {
        int r0 = csr_row[e], r1 = csr_row[e + 2];
        s0 += (float)xh[r0 * 32 + j] * dinv[r0];
        s1 += (float)xh[r1 * 32 + j] * dinv[r1];
    }
    if (e < e1) {
        int r = csr_row[e];
        s0 += (float)xh[r * 32 + j] * dinv[r];
    }
    float s = s0 + s1;
    s += __shfl_xor(s, 32, 64);
    if (lane < 32) {
        float di = dinv[n];
        out[n * 32 + j] = di * s + di * di * (float)xh[n * 32 + j];
    }
}

// xw2: reads fp32 h1raw, writes fp16 Vh = relu(h1+b1) @ g2W
__global__ void xw2_kernel(const float* __restrict__ h1raw, const float* __restrict__ g1b,
                           const float* __restrict__ g2W, _Float16* __restrict__ Vh) {
    int gid = blockIdx.x * 256 + threadIdx.x;
    if (gid >= NN * 32) return;
    int n = gid >> 5, j = gid & 31;
    float s = 0.f;
    for (int k = 0; k < 32; ++k) {
        float h = fmaxf(h1raw[n * 32 + k] + g1b[k], 0.0f);
        s += h * g2W[k * 32 + j];
    }
    Vh[gid] = (_Float16)s;
}

__global__ void pool_seg(const float* __restrict__ h2, const float* __restrict__ g2b,
                         const int* __restrict__ batch, float* __restrict__ pooled,
                         float* __restrict__ counts) {
    int grp = threadIdx.x >> 5, j = threadIdx.x & 31;
    int base = (blockIdx.x * 8 + grp) * 64;
    if (base >= NN) return;
    float bj = g2b[j];
    float acc = 0.f, cnt = 0.f;
    int curg = -1;
    int lim = base + 64;
    if (lim > NN) lim = NN;
    for (int n = base; n < lim; ++n) {
        int g = batch[n];
        if (g != curg) {
            if (curg >= 0) {
                atomicAdd(&pooled[curg * 32 + j], acc);
                if (j == 0) atomicAdd(&counts[curg], cnt);
            }
            curg = g; acc = 0.f; cnt = 0.f;
        }
        acc += fmaxf(h2[n * 32 + j] + bj, 0.f);
        cnt += 1.f;
    }
    if (curg >= 0) {
        atomicAdd(&pooled[curg * 32 + j], acc);
        if (j == 0) atomicAdd(&counts[curg], cnt);
    }
}

__global__ void final_kernel(const float* __restrict__ pooled, const float* __restrict__ counts,
                             const float* __restrict__ clsW, const float* __restrict__ clsb,
                             float* __restrict__ out) {
    int tid = threadIdx.x;
    if (tid >= GG * CC) return;
    int g = tid / CC, cc = tid % CC;
    float inv = 1.0f / fmaxf(counts[g], 1.0f);
    float s = clsb[cc];
    for (int j = 0; j < 32; ++j) s += (pooled[g * 32 + j] * inv) * clsW[j * CC + cc];
    out[g * CC + cc] = s;
}

extern "C" void kernel_launch(void* const* d_in, const int* in_sizes, int n_in,
                              void* d_out, int out_size, void* d_ws, size_t ws_size,
                              hipStream_t stream) {
    const float* x     = (const float*)d_in[0];
    const int*   ei    = (const int*)d_in[1];
    const int*   batch = (const int*)d_in[2];
    const float* fW    = (const float*)d_in[3];
    const float* fb    = (const float*)d_in[4];
    const float* W1    = (const float*)d_in[5];
    const float* b1    = (const float*)d_in[6];
    const float* W2    = (const float*)d_in[7];
    const float* b2    = (const float*)d_in[8];
    const float* g1W   = (const float*)d_in[9];
    const float* g1b   = (const float*)d_in[10];
    const float* g2W   = (const float*)d_in[11];
    const float* g2b   = (const float*)d_in[12];
    const float* clsW  = (const float*)d_in[13];
    const float* clsb  = (const float*)d_in[14];
    float* out = (float*)d_out;

    float4*         xpad    = (float4*)d_ws;                       // 1.6 MB
    unsigned int*   agg     = (unsigned int*)(xpad + NN);          // 32 MB
    int*            csr_row = (int*)(agg + (size_t)STRIP * 320);   // 6.4 MB
    unsigned short* rank    = (unsigned short*)(csr_row + NE);     // 3.2 MB
    int*            cnt     = (int*)(rank + NE);                   // 3.2 MB (8 copies)
    int*            ideg    = cnt + 8 * NN;
    int*            offs    = ideg + NN;
    int*            bsum    = offs + NN + 1;
    float*          dinv    = (float*)(bsum + 512);
    float*          tab     = dinv + NN;
    _Float16*       Mfrag   = (_Float16*)(tab + 16384);            // 40 KB
    _Float16*       xh1     = Mfrag + 20480;                       // 6.4 MB
    float*          U       = (float*)(xh1 + (size_t)NN * 32);     // 12.8 MB (h1raw)
    _Float16*       Vh      = (_Float16*)(U + (size_t)NN * 32);    // 6.4 MB
    float*          h2      = (float*)(Vh + (size_t)NN * 32);      // 12.8 MB
    float*          pooled  = h2 + (size_t)NN * 32;
    float*          counts  = pooled + GG * 32;

    const int nodeBlocks = (NN * 32 + 255) / 256;
    const int edgeBlocks = (NE + 255) / 256;
    const int waveBlocks = (NN + 3) / 4;

    zero_int<<<(8 * NN + 255) / 256, 256, 0, stream>>>(cnt, 8 * NN);
    zero_f<<<(GG * 33 + 255) / 256, 256, 0, stream>>>(pooled, GG * 33);
    precompute_small<<<10, 1024, 0, stream>>>(fW, fb, W1, b1, W2, b2, g1W, tab);
    mfrag_kernel<<<10, 256, 0, stream>>>(tab, Mfrag);

    deg_rank<<<edgeBlocks, 256, 0, stream>>>(ei, cnt, rank);
    scan_phase1<<<SBLK, 256, 0, stream>>>(cnt, ideg, bsum);
    scan_phase2<<<1, 512, 0, stream>>>(bsum);
    scan_phase3<<<SBLK, 256, 0, stream>>>(ideg, bsum, x, offs, dinv, xpad, cnt);
    csr_place<<<edgeBlocks, 256, 0, stream>>>(ei, rank, cnt, csr_row);

    for (int s = 0; s < NN / STRIP; ++s) {
        int ns = s * STRIP, ne2 = ns + STRIP;
        edgeconv_fused<<<2048, 256, 0, stream>>>(xpad, offs, csr_row, tab, agg, ns, ne2);
        int foldWaves = (STRIP + 15) / 16;
        fold_mfma<<<(foldWaves + 3) / 4, 256, 0, stream>>>(agg, Mfrag, xpad, ideg, tab, g1W,
                                                           xh1, ns, ne2);
    }

    prop_wave<<<waveBlocks, 256, 0, stream>>>(offs, csr_row, xh1, dinv, U);   // h1raw
    xw2_kernel<<<nodeBlocks, 256, 0, stream>>>(U, g1b, g2W, Vh);              // xw2 fp16
    prop_wave<<<waveBlocks, 256, 0, stream>>>(offs, csr_row, Vh, dinv, h2);   // h2raw
    pool_seg<<<(NN + 511) / 512, 256, 0, stream>>>(h2, g2b, batch, pooled, counts);
    final_kernel<<<1, 640, 0, stream>>>(pooled, counts, clsW, clsb, out);
}